// Round 12
// baseline (945.777 us; speedup 1.0000x reference)
//
#include <hip/hip_runtime.h>
#include <hip/hip_bf16.h>
#include <math.h>

// EnvelopeWassersteinLoss: n=m=8192, d=64, EPS=0.05, 20 Sinkhorn iterations.
//   prep:     XP,XQ f32 -> bf16 + row sq-norms
//   gemm_max: MFMA GEMM -> per-block max -> bm[]
//   max_red:  bm[4096] -> reg, inv_reg
//   gemm_K:   GEMM again; K = exp(-C/reg); byte code L, BIT-LINEAR decode:
//               K~ = as_float(0x3F700000 - (L<<20))   (1 shift + 1 sub)
//   sink2:    512-thread blocks, 8 rows; each thread's 8x16B code slab lives in
//             32 VGPRs across BOTH phases -> K read ONCE per iteration:
//             phase A: x_i = K v (wave reduce + 8x8 LDS cross-wave) -> u = a/x
//             phase B: y_part[blk] = K^T u from registers, bf16
//   reduce_v: v = b / sum_chunks y_part   (1024 bf16 chunks)
//   loss:     A_i = sum K~ v, B_i = sum ln(K~) K~ v -> tt_i = B_i/A_i
//   final:    out = (-reg/N) * sum_i tt_i

#define NN 8192
#define DD 64
#define EPSV 0.05f
#define NITER 20

typedef __attribute__((ext_vector_type(8))) short short8;            // 8 x bf16
typedef __attribute__((ext_vector_type(8))) unsigned short ushort8;  // 8 x bf16 bits
typedef __attribute__((ext_vector_type(4))) float fx4;

__device__ inline float bf2f(unsigned short u) {
    union { unsigned int i; float f; } x; x.i = ((unsigned int)u) << 16; return x.f;
}
__device__ inline unsigned short f2bf(float f) {
    union { float f; unsigned int i; } x; x.f = f;
    unsigned int r = x.i + 0x7fffu + ((x.i >> 16) & 1u);
    return (unsigned short)(r >> 16);
}
// 2-op decode: K~ = as_float(0x3F700000 - (L<<20))
__device__ inline float decK(unsigned int b) {
    return __uint_as_float(0x3F700000u - (b << 20));
}
__device__ inline void dec4_dot(unsigned int cw, fx4 v, float& acc) {
    acc += decK(cw & 255u) * v[0];
    acc += decK((cw >> 8) & 255u) * v[1];
    acc += decK((cw >> 16) & 255u) * v[2];
    acc += decK(cw >> 24) * v[3];
}
__device__ inline void dec4_axpy(unsigned int cw, float u, fx4& ya) {
    ya[0] += decK(cw & 255u) * u;
    ya[1] += decK((cw >> 8) & 255u) * u;
    ya[2] += decK((cw >> 16) & 255u) * u;
    ya[3] += decK(cw >> 24) * u;
}
__device__ inline void dec4_loss(unsigned int cw, fx4 v, float& accA, float& accB) {
    #pragma unroll
    for (int e = 0; e < 4; ++e) {
        float g = decK((cw >> (8 * e)) & 255u);
        float gv = g * v[e];
        accA += gv;
        accB += __logf(g) * gv;
    }
}

// ---------------- prep: convert + row norms ----------------
__global__ __launch_bounds__(256) void prep_k(const float* __restrict__ XP,
                                              const float* __restrict__ XQ,
                                              unsigned short* __restrict__ XPb,
                                              unsigned short* __restrict__ XQb,
                                              float* __restrict__ pn,
                                              float* __restrict__ qn) {
    int task = blockIdx.x * 4 + (threadIdx.x >> 6);
    int lane = threadIdx.x & 63;
    const float* src; unsigned short* dst; float* nrm; int row;
    if (task < NN) { src = XP; dst = XPb; nrm = pn; row = task; }
    else           { src = XQ; dst = XQb; nrm = qn; row = task - NN; }
    float xv = src[row * DD + lane];
    dst[row * DD + lane] = f2bf(xv);
    float s = xv * xv;
    #pragma unroll
    for (int o = 32; o; o >>= 1) s += __shfl_xor(s, o);
    if (lane == 0) nrm[row] = s;
}

// ---------------- shared GEMM tile: wave computes 64x64 via 4x4 MFMA frags ----------------
__device__ inline void gemm_tile(const unsigned short* __restrict__ XPb,
                                 const unsigned short* __restrict__ XQb,
                                 int R0, int C0, int lane, fx4 acc[4][4]) {
    int r  = lane & 15;
    int ko = (lane >> 4) * 8;
    #pragma unroll
    for (int kk = 0; kk < DD; kk += 32) {
        short8 a[4], b[4];
        #pragma unroll
        for (int m = 0; m < 4; m++)
            a[m] = *(const short8*)(XPb + (R0 + m * 16 + r) * DD + kk + ko);
        #pragma unroll
        for (int n = 0; n < 4; n++)
            b[n] = *(const short8*)(XQb + (C0 + n * 16 + r) * DD + kk + ko);
        #pragma unroll
        for (int m = 0; m < 4; m++)
            #pragma unroll
            for (int n = 0; n < 4; n++)
                acc[m][n] = __builtin_amdgcn_mfma_f32_16x16x32_bf16(a[m], b[n], acc[m][n], 0, 0, 0);
    }
}

// ---------------- pass 1: per-block max of C -> bm[] ----------------
__global__ __launch_bounds__(256) void gemm_max_k(const unsigned short* __restrict__ XPb,
                                                  const unsigned short* __restrict__ XQb,
                                                  const float* __restrict__ pn,
                                                  const float* __restrict__ qn,
                                                  float* __restrict__ bm) {
    int w = threadIdx.x >> 6, wr = w >> 1, wc = w & 1;
    int lane = threadIdx.x & 63;
    int R0 = blockIdx.y * 128 + wr * 64;
    int C0 = blockIdx.x * 128 + wc * 64;
    fx4 acc[4][4] = {};
    gemm_tile(XPb, XQb, R0, C0, lane, acc);

    float pl = pn[R0 + lane], ql = qn[C0 + lane];
    float pr[16], qc[4];
    #pragma unroll
    for (int m = 0; m < 4; m++)
        #pragma unroll
        for (int j = 0; j < 4; j++)
            pr[m * 4 + j] = __shfl(pl, m * 16 + ((lane >> 4) << 2) + j);
    #pragma unroll
    for (int n = 0; n < 4; n++) qc[n] = __shfl(ql, n * 16 + (lane & 15));

    float mx = 0.0f;
    #pragma unroll
    for (int m = 0; m < 4; m++)
        #pragma unroll
        for (int n = 0; n < 4; n++)
            #pragma unroll
            for (int j = 0; j < 4; j++)
                mx = fmaxf(mx, pr[m * 4 + j] + qc[n] - 2.0f * acc[m][n][j]);
    #pragma unroll
    for (int o = 32; o; o >>= 1) mx = fmaxf(mx, __shfl_xor(mx, o));
    __shared__ float wmax[4];
    if (lane == 0) wmax[w] = mx;
    __syncthreads();
    if (threadIdx.x == 0)
        bm[blockIdx.y * 64 + blockIdx.x] = fmaxf(fmaxf(wmax[0], wmax[1]), fmaxf(wmax[2], wmax[3]));
}

// ---------------- reduce bm[4096] -> regbuf {reg, inv_reg} ----------------
__global__ __launch_bounds__(256) void max_red_k(const float* __restrict__ bm,
                                                 float* __restrict__ regbuf) {
    int t = threadIdx.x;
    float mx = 0.0f;
    #pragma unroll
    for (int i = 0; i < 16; ++i) mx = fmaxf(mx, bm[i * 256 + t]);
    #pragma unroll
    for (int o = 32; o; o >>= 1) mx = fmaxf(mx, __shfl_xor(mx, o));
    __shared__ float wmax[4];
    if ((t & 63) == 0) wmax[t >> 6] = mx;
    __syncthreads();
    if (t == 0) {
        float m = fmaxf(fmaxf(wmax[0], wmax[1]), fmaxf(wmax[2], wmax[3]));
        float reg = EPSV * m;
        regbuf[0] = reg;
        regbuf[1] = 1.0f / reg;
    }
}

// ---------------- pass 2: byte code L (bit-linear decode), coalesced via LDS tile ----------------
__global__ __launch_bounds__(256) void gemm_K_k(const unsigned short* __restrict__ XPb,
                                                const unsigned short* __restrict__ XQb,
                                                const float* __restrict__ pn,
                                                const float* __restrict__ qn,
                                                const float* __restrict__ regbuf,
                                                unsigned char* __restrict__ Kb) {
    __shared__ unsigned char tile[128][136];
    int w = threadIdx.x >> 6, wr = w >> 1, wc = w & 1;
    int lane = threadIdx.x & 63;
    int R0 = blockIdx.y * 128 + wr * 64;
    int C0 = blockIdx.x * 128 + wc * 64;
    fx4 acc[4][4] = {};
    gemm_tile(XPb, XQb, R0, C0, lane, acc);

    float inv_reg = regbuf[1];
    float pl = pn[R0 + lane], ql = qn[C0 + lane];
    float pr[16], qc[4];
    #pragma unroll
    for (int m = 0; m < 4; m++)
        #pragma unroll
        for (int j = 0; j < 4; j++)
            pr[m * 4 + j] = __shfl(pl, m * 16 + ((lane >> 4) << 2) + j);
    #pragma unroll
    for (int n = 0; n < 4; n++) qc[n] = __shfl(ql, n * 16 + (lane & 15));

    #pragma unroll
    for (int m = 0; m < 4; m++) {
        #pragma unroll
        for (int n = 0; n < 4; n++) {
            #pragma unroll
            for (int j = 0; j < 4; j++) {
                float c = fmaxf(pr[m * 4 + j] + qc[n] - 2.0f * acc[m][n][j], 0.0f);
                float kv = __expf(-c * inv_reg);
                int L = (0x3F700000 - (int)__float_as_uint(kv) + 0x80000) >> 20;
                L = L < 0 ? 0 : (L > 255 ? 255 : L);
                int lr = wr * 64 + m * 16 + ((lane >> 4) << 2) + j;
                int lc = wc * 64 + n * 16 + (lane & 15);
                tile[lr][lc] = (unsigned char)L;
            }
        }
    }
    __syncthreads();

    int lane16 = threadIdx.x & 15;
    int rowgrp = threadIdx.x >> 4;
    size_t Rg = (size_t)blockIdx.y * 128;
    int Cg = blockIdx.x * 128;
    #pragma unroll
    for (int s = 0; s < 8; ++s) {
        int row = s * 16 + rowgrp;
        uint2 pk = *(const uint2*)&tile[row][lane16 * 8];
        *(uint2*)(Kb + (Rg + row) * NN + Cg + lane16 * 8) = pk;
    }
}

// ---------------- fused Sinkhorn pass: 512 thr, 8 rows, codes live in 32 VGPRs ----------------
// phase A (iter>0): x_i = sum_j K~_ij v_j  -> u_i = (1/N)/x_i
// phase B:          y_part[blk][j] = sum_{i in blk} u_i K~_ij   (bf16), from registers
__global__ __launch_bounds__(512) void sink2_k(const unsigned char* __restrict__ Kb,
                                               const float* __restrict__ vv,
                                               unsigned short* __restrict__ y_part,
                                               int iter) {
    __shared__ float xr[8][8];
    __shared__ float us_sh[8];

    int t = threadIdx.x;
    int w = t >> 6, l = t & 63;
    size_t r0 = (size_t)blockIdx.x * 8;
    int cbase = t * 16;                              // this thread's 16-col window
    const unsigned char* base = Kb + r0 * NN + cbase;

    // codes for 8 rows x 16 cols: 8 x uint4 = 32 VGPR, held through BOTH phases
    uint4 cw[8];
    #pragma unroll
    for (int i = 0; i < 8; ++i)
        cw[i] = *(const uint4*)(base + (size_t)i * NN);

    if (iter != 0) {
        fx4 v0 = *(const fx4*)(vv + cbase);
        fx4 v1 = *(const fx4*)(vv + cbase + 4);
        fx4 v2 = *(const fx4*)(vv + cbase + 8);
        fx4 v3 = *(const fx4*)(vv + cbase + 12);
        #pragma unroll
        for (int i = 0; i < 8; ++i) {
            float a0 = 0.0f, a1 = 0.0f;              // 2 independent chains
            dec4_dot(cw[i].x, v0, a0);
            dec4_dot(cw[i].y, v1, a1);
            dec4_dot(cw[i].z, v2, a0);
            dec4_dot(cw[i].w, v3, a1);
            float a = a0 + a1;
            #pragma unroll
            for (int o = 32; o; o >>= 1) a += __shfl_xor(a, o);
            if (l == 0) xr[i][w] = a;
        }
        __syncthreads();
        if (t < 8) {
            float x = 0.0f;
            #pragma unroll
            for (int k = 0; k < 8; ++k) x += xr[t][k];
            us_sh[t] = (1.0f / (float)NN) / x;
        }
        __syncthreads();
    } else {
        if (t < 8) us_sh[t] = 1.0f / (float)NN;
        __syncthreads();
    }

    // phase B straight from the registers — K is NOT re-read from memory
    fx4 ya0 = {0, 0, 0, 0}, ya1 = {0, 0, 0, 0}, ya2 = {0, 0, 0, 0}, ya3 = {0, 0, 0, 0};
    #pragma unroll
    for (int i = 0; i < 8; ++i) {
        float u = us_sh[i];                          // LDS broadcast read
        dec4_axpy(cw[i].x, u, ya0);
        dec4_axpy(cw[i].y, u, ya1);
        dec4_axpy(cw[i].z, u, ya2);
        dec4_axpy(cw[i].w, u, ya3);
    }
    ushort8 o0, o1;
    #pragma unroll
    for (int e = 0; e < 4; ++e) {
        o0[e]     = f2bf(ya0[e]);
        o0[e + 4] = f2bf(ya1[e]);
        o1[e]     = f2bf(ya2[e]);
        o1[e + 4] = f2bf(ya3[e]);
    }
    unsigned short* yp = y_part + (size_t)blockIdx.x * NN + cbase;
    *(ushort8*)yp = o0;
    *(ushort8*)(yp + 8) = o1;
}

// ---------------- v[j] = b / sum_c y_part[c][j]  (1024 bf16 chunks) ----------------
__global__ __launch_bounds__(256) void reduce_v_k(const unsigned short* __restrict__ y_part,
                                                  float* __restrict__ vv) {
    int t = threadIdx.x;
    int w = t >> 6, l = t & 63;
    int col = blockIdx.x * 64 + l;
    float s = 0.0f;
    #pragma unroll 8
    for (int c = w * 256; c < w * 256 + 256; ++c)
        s += bf2f(y_part[(size_t)c * NN + col]);
    __shared__ float part[4][64];
    part[w][l] = s;
    __syncthreads();
    if (t < 64) {
        float y = part[0][t] + part[1][t] + part[2][t] + part[3][t];
        vv[blockIdx.x * 64 + t] = (1.0f / (float)NN) / y;
    }
}

// ---------------- loss pass: A_i = sum K~ v, B_i = sum ln(K~) K~ v -> tt = B/A ----------------
__global__ __launch_bounds__(256) void loss_k(const unsigned char* __restrict__ Kb,
                                              const float* __restrict__ vv,
                                              float* __restrict__ tt) {
    __shared__ float xrA[4][16];
    __shared__ float xrB[4][16];
    int t = threadIdx.x;
    int w = t >> 6, l = t & 63;
    size_t r0 = (size_t)blockIdx.x * 16;
    int cbase = w * 2048 + l * 16;
    fx4 vr[8];
    #pragma unroll
    for (int it = 0; it < 2; ++it)
        #pragma unroll
        for (int q = 0; q < 4; ++q)
            vr[it * 4 + q] = *(const fx4*)(vv + cbase + it * 1024 + q * 4);

    #pragma unroll
    for (int i = 0; i < 16; ++i) {
        float accA = 0.0f, accB = 0.0f;
        uint4 cbA = *(const uint4*)(Kb + (r0 + i) * NN + cbase);
        uint4 cbB = *(const uint4*)(Kb + (r0 + i) * NN + cbase + 1024);
        dec4_loss(cbA.x, vr[0], accA, accB);
        dec4_loss(cbA.y, vr[1], accA, accB);
        dec4_loss(cbA.z, vr[2], accA, accB);
        dec4_loss(cbA.w, vr[3], accA, accB);
        dec4_loss(cbB.x, vr[4], accA, accB);
        dec4_loss(cbB.y, vr[5], accA, accB);
        dec4_loss(cbB.z, vr[6], accA, accB);
        dec4_loss(cbB.w, vr[7], accA, accB);
        #pragma unroll
        for (int o = 32; o; o >>= 1) {
            accA += __shfl_xor(accA, o);
            accB += __shfl_xor(accB, o);
        }
        if (l == 0) { xrA[w][i] = accA; xrB[w][i] = accB; }
    }
    __syncthreads();
    if (t < 16) {
        float A = xrA[0][t] + xrA[1][t] + xrA[2][t] + xrA[3][t];
        float B = xrB[0][t] + xrB[1][t] + xrB[2][t] + xrB[3][t];
        tt[r0 + t] = B / A;
    }
}

// ---------------- out = (-reg/N) * sum_i tt_i ----------------
__global__ __launch_bounds__(256) void final_loss_k(const float* __restrict__ tt,
                                                    const float* __restrict__ regbuf,
                                                    float* __restrict__ out) {
    int t = threadIdx.x;
    float s = 0.0f;
    for (int i = t; i < NN; i += 256)
        s += tt[i];
    #pragma unroll
    for (int o = 32; o; o >>= 1) s += __shfl_xor(s, o);
    __shared__ float wsum[4];
    if ((t & 63) == 0) wsum[t >> 6] = s;
    __syncthreads();
    if (t == 0)
        out[0] = -regbuf[0] * (wsum[0] + wsum[1] + wsum[2] + wsum[3]) / (float)NN;
}

extern "C" void kernel_launch(void* const* d_in, const int* in_sizes, int n_in,
                              void* d_out, int out_size, void* d_ws, size_t ws_size,
                              hipStream_t stream) {
    const float* XP = (const float*)d_in[0];
    const float* XQ = (const float*)d_in[1];
    float* out = (float*)d_out;

    // workspace layout (~82.5 MiB)
    char* p = (char*)d_ws;
    unsigned char* Kb = (unsigned char*)p;     p += (size_t)NN * NN;          // 64 MiB
    unsigned short* y_part = (unsigned short*)p; p += (size_t)1024 * NN * 2;  // 16 MiB
    unsigned short* XPb = (unsigned short*)p;  p += (size_t)NN * DD * 2;      // 1 MiB
    unsigned short* XQb = (unsigned short*)p;  p += (size_t)NN * DD * 2;      // 1 MiB
    float* pn = (float*)p;                     p += NN * 4;
    float* qn = (float*)p;                     p += NN * 4;
    float* vv = (float*)p;                     p += NN * 4;
    float* tt = (float*)p;                     p += NN * 4;
    float* bm = (float*)p;                     p += 4096 * 4;
    float* regbuf = (float*)p;

    prep_k<<<4096, 256, 0, stream>>>(XP, XQ, XPb, XQb, pn, qn);
    gemm_max_k<<<dim3(64, 64), 256, 0, stream>>>(XPb, XQb, pn, qn, bm);
    max_red_k<<<1, 256, 0, stream>>>(bm, regbuf);
    gemm_K_k<<<dim3(64, 64), 256, 0, stream>>>(XPb, XQb, pn, qn, regbuf, Kb);

    for (int it = 0; it < NITER; ++it) {
        sink2_k<<<1024, 512, 0, stream>>>(Kb, vv, y_part, it);
        reduce_v_k<<<128, 256, 0, stream>>>(y_part, vv);
    }
    loss_k<<<512, 256, 0, stream>>>(Kb, vv, tt);
    final_loss_k<<<1, 256, 0, stream>>>(tt, regbuf, out);
}

// Round 13
// 661.139 us; speedup vs baseline: 1.4305x; 1.4305x over previous
//
#include <hip/hip_runtime.h>
#include <hip/hip_bf16.h>
#include <math.h>

// EnvelopeWassersteinLoss: n=m=8192, d=64, EPS=0.05, 20 Sinkhorn iterations.
//   prep:     XP,XQ f32 -> bf16 + row sq-norms
//   gemm_max: MFMA GEMM -> per-block max -> bm[]
//   max_red:  bm[4096] -> reg, inv_reg
//   gemm_K:   GEMM; K = exp(-C/reg); byte code L, BIT-LINEAR decode:
//               K~ = as_float(0x3F700000 - (L<<20))   (1 shift + 1 sub)
//             Called TWICE: (XP,XQ)->K and (XQ,XP)->KT. MFMA determinism +
//             IEEE add commutativity make KT[j][i] bit-identical to K[i][j].
//   loop:     pure row-gather matvecs, no partials/reduce kernels:
//               mv(KT, u) -> v = (1/N)/(KT u)     [iter 0: u = 1/N const]
//               mv(K, v)  -> u = (1/N)/(K v)
//             one row per wave, 8192 waves, v staged in LDS (conflict-free
//             4-word/lane layout), 32 outstanding K loads per lane.
//   loss:     A_i = sum K~ v, B_i = sum ln(K~) K~ v -> tt_i = B_i/A_i
//   final:    out = (-reg/N) * sum_i tt_i

#define NN 8192
#define DD 64
#define EPSV 0.05f
#define NITER 20

typedef __attribute__((ext_vector_type(8))) short short8;            // 8 x bf16
typedef __attribute__((ext_vector_type(4))) float fx4;

__device__ inline unsigned short f2bf(float f) {
    union { float f; unsigned int i; } x; x.f = f;
    unsigned int r = x.i + 0x7fffu + ((x.i >> 16) & 1u);
    return (unsigned short)(r >> 16);
}
// 2-op decode: K~ = as_float(0x3F700000 - (L<<20))
__device__ inline float decK(unsigned int b) {
    return __uint_as_float(0x3F700000u - (b << 20));
}
__device__ inline void dec4_dot(unsigned int cw, fx4 v, float& acc) {
    acc += decK(cw & 255u) * v[0];
    acc += decK((cw >> 8) & 255u) * v[1];
    acc += decK((cw >> 16) & 255u) * v[2];
    acc += decK(cw >> 24) * v[3];
}
__device__ inline void dec4_loss(unsigned int cw, fx4 v, float& accA, float& accB) {
    #pragma unroll
    for (int e = 0; e < 4; ++e) {
        float g = decK((cw >> (8 * e)) & 255u);
        float gv = g * v[e];
        accA += gv;
        accB += __logf(g) * gv;
    }
}

// ---------------- prep: convert + row norms ----------------
__global__ __launch_bounds__(256) void prep_k(const float* __restrict__ XP,
                                              const float* __restrict__ XQ,
                                              unsigned short* __restrict__ XPb,
                                              unsigned short* __restrict__ XQb,
                                              float* __restrict__ pn,
                                              float* __restrict__ qn) {
    int task = blockIdx.x * 4 + (threadIdx.x >> 6);
    int lane = threadIdx.x & 63;
    const float* src; unsigned short* dst; float* nrm; int row;
    if (task < NN) { src = XP; dst = XPb; nrm = pn; row = task; }
    else           { src = XQ; dst = XQb; nrm = qn; row = task - NN; }
    float xv = src[row * DD + lane];
    dst[row * DD + lane] = f2bf(xv);
    float s = xv * xv;
    #pragma unroll
    for (int o = 32; o; o >>= 1) s += __shfl_xor(s, o);
    if (lane == 0) nrm[row] = s;
}

// ---------------- shared GEMM tile: wave computes 64x64 via 4x4 MFMA frags ----------------
__device__ inline void gemm_tile(const unsigned short* __restrict__ XPb,
                                 const unsigned short* __restrict__ XQb,
                                 int R0, int C0, int lane, fx4 acc[4][4]) {
    int r  = lane & 15;
    int ko = (lane >> 4) * 8;
    #pragma unroll
    for (int kk = 0; kk < DD; kk += 32) {
        short8 a[4], b[4];
        #pragma unroll
        for (int m = 0; m < 4; m++)
            a[m] = *(const short8*)(XPb + (R0 + m * 16 + r) * DD + kk + ko);
        #pragma unroll
        for (int n = 0; n < 4; n++)
            b[n] = *(const short8*)(XQb + (C0 + n * 16 + r) * DD + kk + ko);
        #pragma unroll
        for (int m = 0; m < 4; m++)
            #pragma unroll
            for (int n = 0; n < 4; n++)
                acc[m][n] = __builtin_amdgcn_mfma_f32_16x16x32_bf16(a[m], b[n], acc[m][n], 0, 0, 0);
    }
}

// ---------------- pass 1: per-block max of C -> bm[] ----------------
__global__ __launch_bounds__(256) void gemm_max_k(const unsigned short* __restrict__ XPb,
                                                  const unsigned short* __restrict__ XQb,
                                                  const float* __restrict__ pn,
                                                  const float* __restrict__ qn,
                                                  float* __restrict__ bm) {
    int w = threadIdx.x >> 6, wr = w >> 1, wc = w & 1;
    int lane = threadIdx.x & 63;
    int R0 = blockIdx.y * 128 + wr * 64;
    int C0 = blockIdx.x * 128 + wc * 64;
    fx4 acc[4][4] = {};
    gemm_tile(XPb, XQb, R0, C0, lane, acc);

    float pl = pn[R0 + lane], ql = qn[C0 + lane];
    float pr[16], qc[4];
    #pragma unroll
    for (int m = 0; m < 4; m++)
        #pragma unroll
        for (int j = 0; j < 4; j++)
            pr[m * 4 + j] = __shfl(pl, m * 16 + ((lane >> 4) << 2) + j);
    #pragma unroll
    for (int n = 0; n < 4; n++) qc[n] = __shfl(ql, n * 16 + (lane & 15));

    float mx = 0.0f;
    #pragma unroll
    for (int m = 0; m < 4; m++)
        #pragma unroll
        for (int n = 0; n < 4; n++)
            #pragma unroll
            for (int j = 0; j < 4; j++)
                mx = fmaxf(mx, pr[m * 4 + j] + qc[n] - 2.0f * acc[m][n][j]);
    #pragma unroll
    for (int o = 32; o; o >>= 1) mx = fmaxf(mx, __shfl_xor(mx, o));
    __shared__ float wmax[4];
    if (lane == 0) wmax[w] = mx;
    __syncthreads();
    if (threadIdx.x == 0)
        bm[blockIdx.y * 64 + blockIdx.x] = fmaxf(fmaxf(wmax[0], wmax[1]), fmaxf(wmax[2], wmax[3]));
}

// ---------------- reduce bm[4096] -> regbuf {reg, inv_reg} ----------------
__global__ __launch_bounds__(256) void max_red_k(const float* __restrict__ bm,
                                                 float* __restrict__ regbuf) {
    int t = threadIdx.x;
    float mx = 0.0f;
    #pragma unroll
    for (int i = 0; i < 16; ++i) mx = fmaxf(mx, bm[i * 256 + t]);
    #pragma unroll
    for (int o = 32; o; o >>= 1) mx = fmaxf(mx, __shfl_xor(mx, o));
    __shared__ float wmax[4];
    if ((t & 63) == 0) wmax[t >> 6] = mx;
    __syncthreads();
    if (t == 0) {
        float m = fmaxf(fmaxf(wmax[0], wmax[1]), fmaxf(wmax[2], wmax[3]));
        float reg = EPSV * m;
        regbuf[0] = reg;
        regbuf[1] = 1.0f / reg;
    }
}

// ---------------- pass 2: byte code L (bit-linear decode), coalesced via LDS tile ----------------
__global__ __launch_bounds__(256) void gemm_K_k(const unsigned short* __restrict__ XPb,
                                                const unsigned short* __restrict__ XQb,
                                                const float* __restrict__ pn,
                                                const float* __restrict__ qn,
                                                const float* __restrict__ regbuf,
                                                unsigned char* __restrict__ Kb) {
    __shared__ unsigned char tile[128][136];
    int w = threadIdx.x >> 6, wr = w >> 1, wc = w & 1;
    int lane = threadIdx.x & 63;
    int R0 = blockIdx.y * 128 + wr * 64;
    int C0 = blockIdx.x * 128 + wc * 64;
    fx4 acc[4][4] = {};
    gemm_tile(XPb, XQb, R0, C0, lane, acc);

    float inv_reg = regbuf[1];
    float pl = pn[R0 + lane], ql = qn[C0 + lane];
    float pr[16], qc[4];
    #pragma unroll
    for (int m = 0; m < 4; m++)
        #pragma unroll
        for (int j = 0; j < 4; j++)
            pr[m * 4 + j] = __shfl(pl, m * 16 + ((lane >> 4) << 2) + j);
    #pragma unroll
    for (int n = 0; n < 4; n++) qc[n] = __shfl(ql, n * 16 + (lane & 15));

    #pragma unroll
    for (int m = 0; m < 4; m++) {
        #pragma unroll
        for (int n = 0; n < 4; n++) {
            #pragma unroll
            for (int j = 0; j < 4; j++) {
                float c = fmaxf(pr[m * 4 + j] + qc[n] - 2.0f * acc[m][n][j], 0.0f);
                float kv = __expf(-c * inv_reg);
                int L = (0x3F700000 - (int)__float_as_uint(kv) + 0x80000) >> 20;
                L = L < 0 ? 0 : (L > 255 ? 255 : L);
                int lr = wr * 64 + m * 16 + ((lane >> 4) << 2) + j;
                int lc = wc * 64 + n * 16 + (lane & 15);
                tile[lr][lc] = (unsigned char)L;
            }
        }
    }
    __syncthreads();

    int lane16 = threadIdx.x & 15;
    int rowgrp = threadIdx.x >> 4;
    size_t Rg = (size_t)blockIdx.y * 128;
    int Cg = blockIdx.x * 128;
    #pragma unroll
    for (int s = 0; s < 8; ++s) {
        int row = s * 16 + rowgrp;
        uint2 pk = *(const uint2*)&tile[row][lane16 * 8];
        *(uint2*)(Kb + (Rg + row) * NN + Cg + lane16 * 8) = pk;
    }
}

// ---------------- row-gather matvec: wout[row] = (1/N) / sum_col dec(M[row][col]) * win[col] ----------------
// 512 thr = 8 waves, one row per wave, grid 1024. win staged in LDS
// (4-word/lane layout -> uniform bank load). 32 K-dword loads per lane, all
// issued up front. No cross-block communication.
__global__ __launch_bounds__(512) void mv_k(const unsigned char* __restrict__ M,
                                            const float* __restrict__ win,
                                            float* __restrict__ wout,
                                            int constu) {
    __shared__ float vs[NN];   // 32 KiB
    int t = threadIdx.x;
    if (constu) {
        fx4 c = {1.0f / (float)NN, 1.0f / (float)NN, 1.0f / (float)NN, 1.0f / (float)NN};
        #pragma unroll
        for (int i = 0; i < 4; ++i)
            *(fx4*)(vs + i * 2048 + t * 4) = c;
    } else {
        #pragma unroll
        for (int i = 0; i < 4; ++i)
            *(fx4*)(vs + i * 2048 + t * 4) = *(const fx4*)(win + i * 2048 + t * 4);
    }
    __syncthreads();

    int w = t >> 6, l = t & 63;
    int row = (blockIdx.x << 3) + w;
    const unsigned char* Mr = M + (size_t)row * NN + (l << 2);

    // 32 independent dword loads: lane l covers cols p*256 + 4l + {0..3}
    unsigned int cw[32];
    #pragma unroll
    for (int p = 0; p < 32; ++p)
        cw[p] = *(const unsigned int*)(Mr + p * 256);

    float a0 = 0, a1 = 0, a2 = 0, a3 = 0;
    #pragma unroll
    for (int p = 0; p < 32; p += 4) {
        fx4 v0 = *(const fx4*)(vs + (p + 0) * 256 + (l << 2));
        fx4 v1 = *(const fx4*)(vs + (p + 1) * 256 + (l << 2));
        fx4 v2 = *(const fx4*)(vs + (p + 2) * 256 + (l << 2));
        fx4 v3 = *(const fx4*)(vs + (p + 3) * 256 + (l << 2));
        dec4_dot(cw[p + 0], v0, a0);
        dec4_dot(cw[p + 1], v1, a1);
        dec4_dot(cw[p + 2], v2, a2);
        dec4_dot(cw[p + 3], v3, a3);
    }
    float acc = (a0 + a1) + (a2 + a3);
    #pragma unroll
    for (int o = 32; o; o >>= 1) acc += __shfl_xor(acc, o);
    if (l == 0) wout[row] = (1.0f / (float)NN) / acc;
}

// ---------------- loss pass: A_i = sum K~ v, B_i = sum ln(K~) K~ v -> tt = B/A ----------------
__global__ __launch_bounds__(256) void loss_k(const unsigned char* __restrict__ Kb,
                                              const float* __restrict__ vv,
                                              float* __restrict__ tt) {
    __shared__ float xrA[4][16];
    __shared__ float xrB[4][16];
    int t = threadIdx.x;
    int w = t >> 6, l = t & 63;
    size_t r0 = (size_t)blockIdx.x * 16;
    int cbase = w * 2048 + l * 16;
    fx4 vr[8];
    #pragma unroll
    for (int it = 0; it < 2; ++it)
        #pragma unroll
        for (int q = 0; q < 4; ++q)
            vr[it * 4 + q] = *(const fx4*)(vv + cbase + it * 1024 + q * 4);

    #pragma unroll
    for (int i = 0; i < 16; ++i) {
        float accA = 0.0f, accB = 0.0f;
        uint4 cbA = *(const uint4*)(Kb + (r0 + i) * NN + cbase);
        uint4 cbB = *(const uint4*)(Kb + (r0 + i) * NN + cbase + 1024);
        dec4_loss(cbA.x, vr[0], accA, accB);
        dec4_loss(cbA.y, vr[1], accA, accB);
        dec4_loss(cbA.z, vr[2], accA, accB);
        dec4_loss(cbA.w, vr[3], accA, accB);
        dec4_loss(cbB.x, vr[4], accA, accB);
        dec4_loss(cbB.y, vr[5], accA, accB);
        dec4_loss(cbB.z, vr[6], accA, accB);
        dec4_loss(cbB.w, vr[7], accA, accB);
        #pragma unroll
        for (int o = 32; o; o >>= 1) {
            accA += __shfl_xor(accA, o);
            accB += __shfl_xor(accB, o);
        }
        if (l == 0) { xrA[w][i] = accA; xrB[w][i] = accB; }
    }
    __syncthreads();
    if (t < 16) {
        float A = xrA[0][t] + xrA[1][t] + xrA[2][t] + xrA[3][t];
        float B = xrB[0][t] + xrB[1][t] + xrB[2][t] + xrB[3][t];
        tt[r0 + t] = B / A;
    }
}

// ---------------- out = (-reg/N) * sum_i tt_i ----------------
__global__ __launch_bounds__(256) void final_loss_k(const float* __restrict__ tt,
                                                    const float* __restrict__ regbuf,
                                                    float* __restrict__ out) {
    int t = threadIdx.x;
    float s = 0.0f;
    for (int i = t; i < NN; i += 256)
        s += tt[i];
    #pragma unroll
    for (int o = 32; o; o >>= 1) s += __shfl_xor(s, o);
    __shared__ float wsum[4];
    if ((t & 63) == 0) wsum[t >> 6] = s;
    __syncthreads();
    if (t == 0)
        out[0] = -regbuf[0] * (wsum[0] + wsum[1] + wsum[2] + wsum[3]) / (float)NN;
}

extern "C" void kernel_launch(void* const* d_in, const int* in_sizes, int n_in,
                              void* d_out, int out_size, void* d_ws, size_t ws_size,
                              hipStream_t stream) {
    const float* XP = (const float*)d_in[0];
    const float* XQ = (const float*)d_in[1];
    float* out = (float*)d_out;

    // workspace layout (~130.3 MiB)
    char* p = (char*)d_ws;
    unsigned char* Kb  = (unsigned char*)p;    p += (size_t)NN * NN;          // 64 MiB
    unsigned char* KTb = (unsigned char*)p;    p += (size_t)NN * NN;          // 64 MiB
    unsigned short* XPb = (unsigned short*)p;  p += (size_t)NN * DD * 2;      // 1 MiB
    unsigned short* XQb = (unsigned short*)p;  p += (size_t)NN * DD * 2;      // 1 MiB
    float* pn = (float*)p;                     p += NN * 4;
    float* qn = (float*)p;                     p += NN * 4;
    float* vv = (float*)p;                     p += NN * 4;
    float* uu = (float*)p;                     p += NN * 4;
    float* tt = (float*)p;                     p += NN * 4;
    float* bm = (float*)p;                     p += 4096 * 4;
    float* regbuf = (float*)p;

    prep_k<<<4096, 256, 0, stream>>>(XP, XQ, XPb, XQb, pn, qn);
    gemm_max_k<<<dim3(64, 64), 256, 0, stream>>>(XPb, XQb, pn, qn, bm);
    max_red_k<<<1, 256, 0, stream>>>(bm, regbuf);
    gemm_K_k<<<dim3(64, 64), 256, 0, stream>>>(XPb, XQb, pn, qn, regbuf, Kb);    // K
    gemm_K_k<<<dim3(64, 64), 256, 0, stream>>>(XQb, XPb, qn, pn, regbuf, KTb);   // K^T (bit-identical)

    // v1 = (1/N)/(K^T u0), u0 = 1/N
    mv_k<<<1024, 512, 0, stream>>>(KTb, vv, vv, 1);
    for (int it = 1; it < NITER; ++it) {
        mv_k<<<1024, 512, 0, stream>>>(Kb, vv, uu, 0);    // u_it = (1/N)/(K v_it)
        mv_k<<<1024, 512, 0, stream>>>(KTb, uu, vv, 0);   // v_{it+1} = (1/N)/(K^T u_it)
    }
    loss_k<<<512, 256, 0, stream>>>(Kb, vv, tt);
    final_loss_k<<<1, 256, 0, stream>>>(tt, regbuf, out);
}

// Round 14
// 660.155 us; speedup vs baseline: 1.4327x; 1.0015x over previous
//
#include <hip/hip_runtime.h>
#include <hip/hip_bf16.h>
#include <math.h>

// EnvelopeWassersteinLoss: n=m=8192, d=64, EPS=0.05, 20 Sinkhorn iterations.
//   prep:     XP,XQ f32 -> bf16 + row sq-norms
//   gemm_max: MFMA GEMM -> per-block max -> bm[]
//   max_red:  bm[4096] -> reg, inv_reg
//   gemm_K:   GEMM; K = exp(-C/reg); byte code L, BIT-LINEAR decode:
//               K~ = as_float(0x3F700000 - (L<<20))   (1 shift + 1 sub)
//             Called TWICE: (XP,XQ)->K and (XQ,XP)->KT (bit-identical transpose).
//   loop:     row-gather matvecs mv(KT,u)->v, mv(K,v)->u. mv geometry:
//             block = 8 rows, wave = 1024-col stripe for ALL 8 rows, so the
//             v-fragment (16 VGPR) is LDS-read once and reused 8x. Row sums
//             via LDS partials (vs buffer reused after barrier), wave r
//             reduces row r. 32 coalesced code dwords/lane issued up front.
//   loss:     A_i = sum K~ v, B_i = sum ln(K~) K~ v -> tt_i = B_i/A_i
//   final:    out = (-reg/N) * sum_i tt_i

#define NN 8192
#define DD 64
#define EPSV 0.05f
#define NITER 20

typedef __attribute__((ext_vector_type(8))) short short8;            // 8 x bf16
typedef __attribute__((ext_vector_type(4))) float fx4;

__device__ inline unsigned short f2bf(float f) {
    union { float f; unsigned int i; } x; x.f = f;
    unsigned int r = x.i + 0x7fffu + ((x.i >> 16) & 1u);
    return (unsigned short)(r >> 16);
}
// 2-op decode: K~ = as_float(0x3F700000 - (L<<20))
__device__ inline float decK(unsigned int b) {
    return __uint_as_float(0x3F700000u - (b << 20));
}
__device__ inline void dec4_dot(unsigned int cw, fx4 v, float& acc) {
    acc += decK(cw & 255u) * v[0];
    acc += decK((cw >> 8) & 255u) * v[1];
    acc += decK((cw >> 16) & 255u) * v[2];
    acc += decK(cw >> 24) * v[3];
}
__device__ inline void dec4_loss(unsigned int cw, fx4 v, float& accA, float& accB) {
    #pragma unroll
    for (int e = 0; e < 4; ++e) {
        float g = decK((cw >> (8 * e)) & 255u);
        float gv = g * v[e];
        accA += gv;
        accB += __logf(g) * gv;
    }
}

// ---------------- prep: convert + row norms ----------------
__global__ __launch_bounds__(256) void prep_k(const float* __restrict__ XP,
                                              const float* __restrict__ XQ,
                                              unsigned short* __restrict__ XPb,
                                              unsigned short* __restrict__ XQb,
                                              float* __restrict__ pn,
                                              float* __restrict__ qn) {
    int task = blockIdx.x * 4 + (threadIdx.x >> 6);
    int lane = threadIdx.x & 63;
    const float* src; unsigned short* dst; float* nrm; int row;
    if (task < NN) { src = XP; dst = XPb; nrm = pn; row = task; }
    else           { src = XQ; dst = XQb; nrm = qn; row = task - NN; }
    float xv = src[row * DD + lane];
    dst[row * DD + lane] = f2bf(xv);
    float s = xv * xv;
    #pragma unroll
    for (int o = 32; o; o >>= 1) s += __shfl_xor(s, o);
    if (lane == 0) nrm[row] = s;
}

// ---------------- shared GEMM tile: wave computes 64x64 via 4x4 MFMA frags ----------------
__device__ inline void gemm_tile(const unsigned short* __restrict__ XPb,
                                 const unsigned short* __restrict__ XQb,
                                 int R0, int C0, int lane, fx4 acc[4][4]) {
    int r  = lane & 15;
    int ko = (lane >> 4) * 8;
    #pragma unroll
    for (int kk = 0; kk < DD; kk += 32) {
        short8 a[4], b[4];
        #pragma unroll
        for (int m = 0; m < 4; m++)
            a[m] = *(const short8*)(XPb + (R0 + m * 16 + r) * DD + kk + ko);
        #pragma unroll
        for (int n = 0; n < 4; n++)
            b[n] = *(const short8*)(XQb + (C0 + n * 16 + r) * DD + kk + ko);
        #pragma unroll
        for (int m = 0; m < 4; m++)
            #pragma unroll
            for (int n = 0; n < 4; n++)
                acc[m][n] = __builtin_amdgcn_mfma_f32_16x16x32_bf16(a[m], b[n], acc[m][n], 0, 0, 0);
    }
}

// ---------------- pass 1: per-block max of C -> bm[] ----------------
__global__ __launch_bounds__(256) void gemm_max_k(const unsigned short* __restrict__ XPb,
                                                  const unsigned short* __restrict__ XQb,
                                                  const float* __restrict__ pn,
                                                  const float* __restrict__ qn,
                                                  float* __restrict__ bm) {
    int w = threadIdx.x >> 6, wr = w >> 1, wc = w & 1;
    int lane = threadIdx.x & 63;
    int R0 = blockIdx.y * 128 + wr * 64;
    int C0 = blockIdx.x * 128 + wc * 64;
    fx4 acc[4][4] = {};
    gemm_tile(XPb, XQb, R0, C0, lane, acc);

    float pl = pn[R0 + lane], ql = qn[C0 + lane];
    float pr[16], qc[4];
    #pragma unroll
    for (int m = 0; m < 4; m++)
        #pragma unroll
        for (int j = 0; j < 4; j++)
            pr[m * 4 + j] = __shfl(pl, m * 16 + ((lane >> 4) << 2) + j);
    #pragma unroll
    for (int n = 0; n < 4; n++) qc[n] = __shfl(ql, n * 16 + (lane & 15));

    float mx = 0.0f;
    #pragma unroll
    for (int m = 0; m < 4; m++)
        #pragma unroll
        for (int n = 0; n < 4; n++)
            #pragma unroll
            for (int j = 0; j < 4; j++)
                mx = fmaxf(mx, pr[m * 4 + j] + qc[n] - 2.0f * acc[m][n][j]);
    #pragma unroll
    for (int o = 32; o; o >>= 1) mx = fmaxf(mx, __shfl_xor(mx, o));
    __shared__ float wmax[4];
    if (lane == 0) wmax[w] = mx;
    __syncthreads();
    if (threadIdx.x == 0)
        bm[blockIdx.y * 64 + blockIdx.x] = fmaxf(fmaxf(wmax[0], wmax[1]), fmaxf(wmax[2], wmax[3]));
}

// ---------------- reduce bm[4096] -> regbuf {reg, inv_reg} ----------------
__global__ __launch_bounds__(256) void max_red_k(const float* __restrict__ bm,
                                                 float* __restrict__ regbuf) {
    int t = threadIdx.x;
    float mx = 0.0f;
    #pragma unroll
    for (int i = 0; i < 16; ++i) mx = fmaxf(mx, bm[i * 256 + t]);
    #pragma unroll
    for (int o = 32; o; o >>= 1) mx = fmaxf(mx, __shfl_xor(mx, o));
    __shared__ float wmax[4];
    if ((t & 63) == 0) wmax[t >> 6] = mx;
    __syncthreads();
    if (t == 0) {
        float m = fmaxf(fmaxf(wmax[0], wmax[1]), fmaxf(wmax[2], wmax[3]));
        float reg = EPSV * m;
        regbuf[0] = reg;
        regbuf[1] = 1.0f / reg;
    }
}

// ---------------- pass 2: byte code L (bit-linear decode), coalesced via LDS tile ----------------
__global__ __launch_bounds__(256) void gemm_K_k(const unsigned short* __restrict__ XPb,
                                                const unsigned short* __restrict__ XQb,
                                                const float* __restrict__ pn,
                                                const float* __restrict__ qn,
                                                const float* __restrict__ regbuf,
                                                unsigned char* __restrict__ Kb) {
    __shared__ unsigned char tile[128][136];
    int w = threadIdx.x >> 6, wr = w >> 1, wc = w & 1;
    int lane = threadIdx.x & 63;
    int R0 = blockIdx.y * 128 + wr * 64;
    int C0 = blockIdx.x * 128 + wc * 64;
    fx4 acc[4][4] = {};
    gemm_tile(XPb, XQb, R0, C0, lane, acc);

    float inv_reg = regbuf[1];
    float pl = pn[R0 + lane], ql = qn[C0 + lane];
    float pr[16], qc[4];
    #pragma unroll
    for (int m = 0; m < 4; m++)
        #pragma unroll
        for (int j = 0; j < 4; j++)
            pr[m * 4 + j] = __shfl(pl, m * 16 + ((lane >> 4) << 2) + j);
    #pragma unroll
    for (int n = 0; n < 4; n++) qc[n] = __shfl(ql, n * 16 + (lane & 15));

    #pragma unroll
    for (int m = 0; m < 4; m++) {
        #pragma unroll
        for (int n = 0; n < 4; n++) {
            #pragma unroll
            for (int j = 0; j < 4; j++) {
                float c = fmaxf(pr[m * 4 + j] + qc[n] - 2.0f * acc[m][n][j], 0.0f);
                float kv = __expf(-c * inv_reg);
                int L = (0x3F700000 - (int)__float_as_uint(kv) + 0x80000) >> 20;
                L = L < 0 ? 0 : (L > 255 ? 255 : L);
                int lr = wr * 64 + m * 16 + ((lane >> 4) << 2) + j;
                int lc = wc * 64 + n * 16 + (lane & 15);
                tile[lr][lc] = (unsigned char)L;
            }
        }
    }
    __syncthreads();

    int lane16 = threadIdx.x & 15;
    int rowgrp = threadIdx.x >> 4;
    size_t Rg = (size_t)blockIdx.y * 128;
    int Cg = blockIdx.x * 128;
    #pragma unroll
    for (int s = 0; s < 8; ++s) {
        int row = s * 16 + rowgrp;
        uint2 pk = *(const uint2*)&tile[row][lane16 * 8];
        *(uint2*)(Kb + (Rg + row) * NN + Cg + lane16 * 8) = pk;
    }
}

// ---------------- row-gather matvec, stripe geometry ----------------
// block = 8 rows, 512 thr. Wave w covers cols [1024w,1024w+1024) of ALL 8 rows.
// v fragment (4 x fx4) LDS-read ONCE, reused for 8 rows. Row sums via LDS
// partials (vs reused after barrier); wave r reduces row r.
__global__ __launch_bounds__(512) void mv_k(const unsigned char* __restrict__ M,
                                            const float* __restrict__ win,
                                            float* __restrict__ wout,
                                            int constu) {
    __shared__ float vs[NN];   // 32 KiB; reused as xp[8][8][64] after 2nd barrier
    int t = threadIdx.x;
    if (constu) {
        fx4 c = {1.0f / (float)NN, 1.0f / (float)NN, 1.0f / (float)NN, 1.0f / (float)NN};
        #pragma unroll
        for (int i = 0; i < 4; ++i)
            *(fx4*)(vs + i * 2048 + t * 4) = c;
    } else {
        #pragma unroll
        for (int i = 0; i < 4; ++i)
            *(fx4*)(vs + i * 2048 + t * 4) = *(const fx4*)(win + i * 2048 + t * 4);
    }
    __syncthreads();

    int w = t >> 6, l = t & 63;
    int row0 = blockIdx.x << 3;
    int cb = (w << 10) + (l << 2);                    // stripe base + lane cols
    const unsigned char* Mp = M + (size_t)row0 * NN + cb;

    // 32 coalesced dword loads (8 rows x 4 stripe-chunks), issued up front
    unsigned int cw[8][4];
    #pragma unroll
    for (int r = 0; r < 8; ++r)
        #pragma unroll
        for (int p = 0; p < 4; ++p)
            cw[r][p] = *(const unsigned int*)(Mp + (size_t)r * NN + (p << 8));

    // v fragment: 16 floats, conflict-free b128 reads, reused for all 8 rows
    fx4 v0 = *(const fx4*)(vs + cb);
    fx4 v1 = *(const fx4*)(vs + cb + 256);
    fx4 v2 = *(const fx4*)(vs + cb + 512);
    fx4 v3 = *(const fx4*)(vs + cb + 768);

    float pr[8];
    #pragma unroll
    for (int r = 0; r < 8; ++r) {
        float a0 = 0.0f, a1 = 0.0f;
        dec4_dot(cw[r][0], v0, a0);
        dec4_dot(cw[r][1], v1, a1);
        dec4_dot(cw[r][2], v2, a0);
        dec4_dot(cw[r][3], v3, a1);
        pr[r] = a0 + a1;
    }

    __syncthreads();                                  // all v reads done; alias xp onto vs
    float* xp = vs;                                   // xp[w][r][l] = [8][8][64]
    #pragma unroll
    for (int r = 0; r < 8; ++r)
        xp[(w << 9) + (r << 6) + l] = pr[r];
    __syncthreads();

    // wave w reduces row w: 512 partials = 8 wave-chunks x 64 lanes
    float s = 0.0f;
    #pragma unroll
    for (int q = 0; q < 8; ++q)
        s += xp[(q << 9) + (w << 6) + l];
    #pragma unroll
    for (int o = 32; o; o >>= 1) s += __shfl_xor(s, o);
    if (l == 0) wout[row0 + w] = (1.0f / (float)NN) / s;
}

// ---------------- loss pass: A_i = sum K~ v, B_i = sum ln(K~) K~ v -> tt = B/A ----------------
__global__ __launch_bounds__(256) void loss_k(const unsigned char* __restrict__ Kb,
                                              const float* __restrict__ vv,
                                              float* __restrict__ tt) {
    __shared__ float xrA[4][16];
    __shared__ float xrB[4][16];
    int t = threadIdx.x;
    int w = t >> 6, l = t & 63;
    size_t r0 = (size_t)blockIdx.x * 16;
    int cbase = w * 2048 + l * 16;
    fx4 vr[8];
    #pragma unroll
    for (int it = 0; it < 2; ++it)
        #pragma unroll
        for (int q = 0; q < 4; ++q)
            vr[it * 4 + q] = *(const fx4*)(vv + cbase + it * 1024 + q * 4);

    #pragma unroll
    for (int i = 0; i < 16; ++i) {
        float accA = 0.0f, accB = 0.0f;
        uint4 cbA = *(const uint4*)(Kb + (r0 + i) * NN + cbase);
        uint4 cbB = *(const uint4*)(Kb + (r0 + i) * NN + cbase + 1024);
        dec4_loss(cbA.x, vr[0], accA, accB);
        dec4_loss(cbA.y, vr[1], accA, accB);
        dec4_loss(cbA.z, vr[2], accA, accB);
        dec4_loss(cbA.w, vr[3], accA, accB);
        dec4_loss(cbB.x, vr[4], accA, accB);
        dec4_loss(cbB.y, vr[5], accA, accB);
        dec4_loss(cbB.z, vr[6], accA, accB);
        dec4_loss(cbB.w, vr[7], accA, accB);
        #pragma unroll
        for (int o = 32; o; o >>= 1) {
            accA += __shfl_xor(accA, o);
            accB += __shfl_xor(accB, o);
        }
        if (l == 0) { xrA[w][i] = accA; xrB[w][i] = accB; }
    }
    __syncthreads();
    if (t < 16) {
        float A = xrA[0][t] + xrA[1][t] + xrA[2][t] + xrA[3][t];
        float B = xrB[0][t] + xrB[1][t] + xrB[2][t] + xrB[3][t];
        tt[r0 + t] = B / A;
    }
}

// ---------------- out = (-reg/N) * sum_i tt_i ----------------
__global__ __launch_bounds__(256) void final_loss_k(const float* __restrict__ tt,
                                                    const float* __restrict__ regbuf,
                                                    float* __restrict__ out) {
    int t = threadIdx.x;
    float s = 0.0f;
    for (int i = t; i < NN; i += 256)
        s += tt[i];
    #pragma unroll
    for (int o = 32; o; o >>= 1) s += __shfl_xor(s, o);
    __shared__ float wsum[4];
    if ((t & 63) == 0) wsum[t >> 6] = s;
    __syncthreads();
    if (t == 0)
        out[0] = -regbuf[0] * (wsum[0] + wsum[1] + wsum[2] + wsum[3]) / (float)NN;
}

extern "C" void kernel_launch(void* const* d_in, const int* in_sizes, int n_in,
                              void* d_out, int out_size, void* d_ws, size_t ws_size,
                              hipStream_t stream) {
    const float* XP = (const float*)d_in[0];
    const float* XQ = (const float*)d_in[1];
    float* out = (float*)d_out;

    // workspace layout (~130.3 MiB)
    char* p = (char*)d_ws;
    unsigned char* Kb  = (unsigned char*)p;    p += (size_t)NN * NN;          // 64 MiB
    unsigned char* KTb = (unsigned char*)p;    p += (size_t)NN * NN;          // 64 MiB
    unsigned short* XPb = (unsigned short*)p;  p += (size_t)NN * DD * 2;      // 1 MiB
    unsigned short* XQb = (unsigned short*)p;  p += (size_t)NN * DD * 2;      // 1 MiB
    float* pn = (float*)p;                     p += NN * 4;
    float* qn = (float*)p;                     p += NN * 4;
    float* vv = (float*)p;                     p += NN * 4;
    float* uu = (float*)p;                     p += NN * 4;
    float* tt = (float*)p;                     p += NN * 4;
    float* bm = (float*)p;                     p += 4096 * 4;
    float* regbuf = (float*)p;

    prep_k<<<4096, 256, 0, stream>>>(XP, XQ, XPb, XQb, pn, qn);
    gemm_max_k<<<dim3(64, 64), 256, 0, stream>>>(XPb, XQb, pn, qn, bm);
    max_red_k<<<1, 256, 0, stream>>>(bm, regbuf);
    gemm_K_k<<<dim3(64, 64), 256, 0, stream>>>(XPb, XQb, pn, qn, regbuf, Kb);    // K
    gemm_K_k<<<dim3(64, 64), 256, 0, stream>>>(XQb, XPb, qn, pn, regbuf, KTb);   // K^T (bit-identical)

    // v1 = (1/N)/(K^T u0), u0 = 1/N
    mv_k<<<1024, 512, 0, stream>>>(KTb, vv, vv, 1);
    for (int it = 1; it < NITER; ++it) {
        mv_k<<<1024, 512, 0, stream>>>(Kb, vv, uu, 0);    // u_it = (1/N)/(K v_it)
        mv_k<<<1024, 512, 0, stream>>>(KTb, uu, vv, 0);   // v_{it+1} = (1/N)/(K^T u_it)
    }
    loss_k<<<512, 256, 0, stream>>>(Kb, vv, tt);
    final_loss_k<<<1, 256, 0, stream>>>(tt, regbuf, out);
}

// Round 15
// 617.884 us; speedup vs baseline: 1.5307x; 1.0684x over previous
//
#include <hip/hip_runtime.h>
#include <hip/hip_bf16.h>
#include <math.h>

// EnvelopeWassersteinLoss: n=m=8192, d=64, EPS=0.05, 20 Sinkhorn iterations.
//   prep:     XP,XQ f32 -> bf16 + row sq-norms
//   gemm_max: MFMA GEMM -> per-block max -> bm[]
//   max_red:  bm[4096] -> reg, inv_reg
//   gemm_K:   GEMM; K = exp(-C/reg); byte code L, BIT-LINEAR decode:
//               K~ = as_float(0x3F700000 - (L<<20))   (1 shift + 1 sub)
//             ONE pass writes BOTH K and KT (second LDS tile, transposed).
//   loop:     row-gather matvecs mv(KT,u)->v, mv(K,v)->u.
//             mv v2: block = 8 rows x 512 thr; lane owns 16 CONTIGUOUS cols;
//             codes = 8 x uint4 (1KB/wave-inst), v = 4 x fx4 straight from
//             global (L2 broadcast, no LDS staging). LDS only for the 16KB
//             cross-wave row-partial exchange.
//   loss:     A_i = sum K~ v, B_i = sum ln(K~) K~ v -> tt_i = B_i/A_i
//   final:    out = (-reg/N) * sum_i tt_i

#define NN 8192
#define DD 64
#define EPSV 0.05f
#define NITER 20

typedef __attribute__((ext_vector_type(8))) short short8;            // 8 x bf16
typedef __attribute__((ext_vector_type(4))) float fx4;

__device__ inline unsigned short f2bf(float f) {
    union { float f; unsigned int i; } x; x.f = f;
    unsigned int r = x.i + 0x7fffu + ((x.i >> 16) & 1u);
    return (unsigned short)(r >> 16);
}
// 2-op decode: K~ = as_float(0x3F700000 - (L<<20))
__device__ inline float decK(unsigned int b) {
    return __uint_as_float(0x3F700000u - (b << 20));
}
__device__ inline void dec4_dot(unsigned int cw, fx4 v, float& acc) {
    acc += decK(cw & 255u) * v[0];
    acc += decK((cw >> 8) & 255u) * v[1];
    acc += decK((cw >> 16) & 255u) * v[2];
    acc += decK(cw >> 24) * v[3];
}
__device__ inline void dec4_loss(unsigned int cw, fx4 v, float& accA, float& accB) {
    #pragma unroll
    for (int e = 0; e < 4; ++e) {
        float g = decK((cw >> (8 * e)) & 255u);
        float gv = g * v[e];
        accA += gv;
        accB += __logf(g) * gv;
    }
}

// ---------------- prep: convert + row norms ----------------
__global__ __launch_bounds__(256) void prep_k(const float* __restrict__ XP,
                                              const float* __restrict__ XQ,
                                              unsigned short* __restrict__ XPb,
                                              unsigned short* __restrict__ XQb,
                                              float* __restrict__ pn,
                                              float* __restrict__ qn) {
    int task = blockIdx.x * 4 + (threadIdx.x >> 6);
    int lane = threadIdx.x & 63;
    const float* src; unsigned short* dst; float* nrm; int row;
    if (task < NN) { src = XP; dst = XPb; nrm = pn; row = task; }
    else           { src = XQ; dst = XQb; nrm = qn; row = task - NN; }
    float xv = src[row * DD + lane];
    dst[row * DD + lane] = f2bf(xv);
    float s = xv * xv;
    #pragma unroll
    for (int o = 32; o; o >>= 1) s += __shfl_xor(s, o);
    if (lane == 0) nrm[row] = s;
}

// ---------------- shared GEMM tile: wave computes 64x64 via 4x4 MFMA frags ----------------
__device__ inline void gemm_tile(const unsigned short* __restrict__ XPb,
                                 const unsigned short* __restrict__ XQb,
                                 int R0, int C0, int lane, fx4 acc[4][4]) {
    int r  = lane & 15;
    int ko = (lane >> 4) * 8;
    #pragma unroll
    for (int kk = 0; kk < DD; kk += 32) {
        short8 a[4], b[4];
        #pragma unroll
        for (int m = 0; m < 4; m++)
            a[m] = *(const short8*)(XPb + (R0 + m * 16 + r) * DD + kk + ko);
        #pragma unroll
        for (int n = 0; n < 4; n++)
            b[n] = *(const short8*)(XQb + (C0 + n * 16 + r) * DD + kk + ko);
        #pragma unroll
        for (int m = 0; m < 4; m++)
            #pragma unroll
            for (int n = 0; n < 4; n++)
                acc[m][n] = __builtin_amdgcn_mfma_f32_16x16x32_bf16(a[m], b[n], acc[m][n], 0, 0, 0);
    }
}

// ---------------- pass 1: per-block max of C -> bm[] ----------------
__global__ __launch_bounds__(256) void gemm_max_k(const unsigned short* __restrict__ XPb,
                                                  const unsigned short* __restrict__ XQb,
                                                  const float* __restrict__ pn,
                                                  const float* __restrict__ qn,
                                                  float* __restrict__ bm) {
    int w = threadIdx.x >> 6, wr = w >> 1, wc = w & 1;
    int lane = threadIdx.x & 63;
    int R0 = blockIdx.y * 128 + wr * 64;
    int C0 = blockIdx.x * 128 + wc * 64;
    fx4 acc[4][4] = {};
    gemm_tile(XPb, XQb, R0, C0, lane, acc);

    float pl = pn[R0 + lane], ql = qn[C0 + lane];
    float pr[16], qc[4];
    #pragma unroll
    for (int m = 0; m < 4; m++)
        #pragma unroll
        for (int j = 0; j < 4; j++)
            pr[m * 4 + j] = __shfl(pl, m * 16 + ((lane >> 4) << 2) + j);
    #pragma unroll
    for (int n = 0; n < 4; n++) qc[n] = __shfl(ql, n * 16 + (lane & 15));

    float mx = 0.0f;
    #pragma unroll
    for (int m = 0; m < 4; m++)
        #pragma unroll
        for (int n = 0; n < 4; n++)
            #pragma unroll
            for (int j = 0; j < 4; j++)
                mx = fmaxf(mx, pr[m * 4 + j] + qc[n] - 2.0f * acc[m][n][j]);
    #pragma unroll
    for (int o = 32; o; o >>= 1) mx = fmaxf(mx, __shfl_xor(mx, o));
    __shared__ float wmax[4];
    if (lane == 0) wmax[w] = mx;
    __syncthreads();
    if (threadIdx.x == 0)
        bm[blockIdx.y * 64 + blockIdx.x] = fmaxf(fmaxf(wmax[0], wmax[1]), fmaxf(wmax[2], wmax[3]));
}

// ---------------- reduce bm[4096] -> regbuf {reg, inv_reg} ----------------
__global__ __launch_bounds__(256) void max_red_k(const float* __restrict__ bm,
                                                 float* __restrict__ regbuf) {
    int t = threadIdx.x;
    float mx = 0.0f;
    #pragma unroll
    for (int i = 0; i < 16; ++i) mx = fmaxf(mx, bm[i * 256 + t]);
    #pragma unroll
    for (int o = 32; o; o >>= 1) mx = fmaxf(mx, __shfl_xor(mx, o));
    __shared__ float wmax[4];
    if ((t & 63) == 0) wmax[t >> 6] = mx;
    __syncthreads();
    if (t == 0) {
        float m = fmaxf(fmaxf(wmax[0], wmax[1]), fmaxf(wmax[2], wmax[3]));
        float reg = EPSV * m;
        regbuf[0] = reg;
        regbuf[1] = 1.0f / reg;
    }
}

// ---------------- pass 2: byte codes; ONE pass stores BOTH K and KT ----------------
__global__ __launch_bounds__(256) void gemm_K_k(const unsigned short* __restrict__ XPb,
                                                const unsigned short* __restrict__ XQb,
                                                const float* __restrict__ pn,
                                                const float* __restrict__ qn,
                                                const float* __restrict__ regbuf,
                                                unsigned char* __restrict__ Kb,
                                                unsigned char* __restrict__ KTb) {
    __shared__ unsigned char tile[128][136];
    __shared__ unsigned char tileT[128][136];
    int w = threadIdx.x >> 6, wr = w >> 1, wc = w & 1;
    int lane = threadIdx.x & 63;
    int R0 = blockIdx.y * 128 + wr * 64;
    int C0 = blockIdx.x * 128 + wc * 64;
    fx4 acc[4][4] = {};
    gemm_tile(XPb, XQb, R0, C0, lane, acc);

    float inv_reg = regbuf[1];
    float pl = pn[R0 + lane], ql = qn[C0 + lane];
    float pr[16], qc[4];
    #pragma unroll
    for (int m = 0; m < 4; m++)
        #pragma unroll
        for (int j = 0; j < 4; j++)
            pr[m * 4 + j] = __shfl(pl, m * 16 + ((lane >> 4) << 2) + j);
    #pragma unroll
    for (int n = 0; n < 4; n++) qc[n] = __shfl(ql, n * 16 + (lane & 15));

    #pragma unroll
    for (int m = 0; m < 4; m++) {
        #pragma unroll
        for (int n = 0; n < 4; n++) {
            #pragma unroll
            for (int j = 0; j < 4; j++) {
                float c = fmaxf(pr[m * 4 + j] + qc[n] - 2.0f * acc[m][n][j], 0.0f);
                float kv = __expf(-c * inv_reg);
                int L = (0x3F700000 - (int)__float_as_uint(kv) + 0x80000) >> 20;
                L = L < 0 ? 0 : (L > 255 ? 255 : L);
                int lr = wr * 64 + m * 16 + ((lane >> 4) << 2) + j;
                int lc = wc * 64 + n * 16 + (lane & 15);
                tile[lr][lc]  = (unsigned char)L;
                tileT[lc][lr] = (unsigned char)L;
            }
        }
    }
    __syncthreads();

    int lane16 = threadIdx.x & 15;
    int rowgrp = threadIdx.x >> 4;
    size_t Rg = (size_t)blockIdx.y * 128;
    size_t Cg = (size_t)blockIdx.x * 128;
    #pragma unroll
    for (int s = 0; s < 8; ++s) {
        int row = s * 16 + rowgrp;
        uint2 pk = *(const uint2*)&tile[row][lane16 * 8];
        *(uint2*)(Kb + (Rg + row) * NN + Cg + lane16 * 8) = pk;
        uint2 pt = *(const uint2*)&tileT[row][lane16 * 8];
        *(uint2*)(KTb + (Cg + row) * NN + Rg + lane16 * 8) = pt;
    }
}

// ---------------- row-gather matvec v2: contiguous 16-col lanes, no v-LDS ----------------
// block = 8 rows, 512 thr. Wave w covers cols [1024w,1024w+1024); lane l owns
// cols [cb, cb+16). codes: 8 x uint4 (coalesced 1KB/inst). v: 4 x fx4 from
// GLOBAL (L2 broadcast). LDS only for cross-wave row partials (16KB).
__global__ __launch_bounds__(512) void mv_k(const unsigned char* __restrict__ M,
                                            const float* __restrict__ win,
                                            float* __restrict__ wout,
                                            int constu) {
    __shared__ float xp[8 * 8 * 64];   // [wave][row][lane] = 16 KiB
    int t = threadIdx.x;
    int w = t >> 6, l = t & 63;
    int row0 = blockIdx.x << 3;
    int cb = (w << 10) + (l << 4);                    // 16 contiguous cols per lane
    const unsigned char* Mp = M + (size_t)row0 * NN + cb;

    // 8 coalesced uint4 code loads (one per row), issued up front
    uint4 cw[8];
    #pragma unroll
    for (int r = 0; r < 8; ++r)
        cw[r] = *(const uint4*)(Mp + (size_t)r * NN);

    fx4 v0, v1, v2, v3;
    if (constu) {
        fx4 c = {1.0f / (float)NN, 1.0f / (float)NN, 1.0f / (float)NN, 1.0f / (float)NN};
        v0 = c; v1 = c; v2 = c; v3 = c;
    } else {
        v0 = *(const fx4*)(win + cb);
        v1 = *(const fx4*)(win + cb + 4);
        v2 = *(const fx4*)(win + cb + 8);
        v3 = *(const fx4*)(win + cb + 12);
    }

    #pragma unroll
    for (int r = 0; r < 8; ++r) {
        float a0 = 0.0f, a1 = 0.0f;
        dec4_dot(cw[r].x, v0, a0);
        dec4_dot(cw[r].y, v1, a1);
        dec4_dot(cw[r].z, v2, a0);
        dec4_dot(cw[r].w, v3, a1);
        xp[(w << 9) + (r << 6) + l] = a0 + a1;
    }
    __syncthreads();

    // wave w reduces row w: 8 wave-chunks x 64 lanes
    float s = 0.0f;
    #pragma unroll
    for (int q = 0; q < 8; ++q)
        s += xp[(q << 9) + (w << 6) + l];
    #pragma unroll
    for (int o = 32; o; o >>= 1) s += __shfl_xor(s, o);
    if (l == 0) wout[row0 + w] = (1.0f / (float)NN) / s;
}

// ---------------- loss pass: A_i = sum K~ v, B_i = sum ln(K~) K~ v -> tt = B/A ----------------
__global__ __launch_bounds__(256) void loss_k(const unsigned char* __restrict__ Kb,
                                              const float* __restrict__ vv,
                                              float* __restrict__ tt) {
    __shared__ float xrA[4][16];
    __shared__ float xrB[4][16];
    int t = threadIdx.x;
    int w = t >> 6, l = t & 63;
    size_t r0 = (size_t)blockIdx.x * 16;
    int cbase = w * 2048 + l * 16;
    fx4 vr[8];
    #pragma unroll
    for (int it = 0; it < 2; ++it)
        #pragma unroll
        for (int q = 0; q < 4; ++q)
            vr[it * 4 + q] = *(const fx4*)(vv + cbase + it * 1024 + q * 4);

    #pragma unroll
    for (int i = 0; i < 16; ++i) {
        float accA = 0.0f, accB = 0.0f;
        uint4 cbA = *(const uint4*)(Kb + (r0 + i) * NN + cbase);
        uint4 cbB = *(const uint4*)(Kb + (r0 + i) * NN + cbase + 1024);
        dec4_loss(cbA.x, vr[0], accA, accB);
        dec4_loss(cbA.y, vr[1], accA, accB);
        dec4_loss(cbA.z, vr[2], accA, accB);
        dec4_loss(cbA.w, vr[3], accA, accB);
        dec4_loss(cbB.x, vr[4], accA, accB);
        dec4_loss(cbB.y, vr[5], accA, accB);
        dec4_loss(cbB.z, vr[6], accA, accB);
        dec4_loss(cbB.w, vr[7], accA, accB);
        #pragma unroll
        for (int o = 32; o; o >>= 1) {
            accA += __shfl_xor(accA, o);
            accB += __shfl_xor(accB, o);
        }
        if (l == 0) { xrA[w][i] = accA; xrB[w][i] = accB; }
    }
    __syncthreads();
    if (t < 16) {
        float A = xrA[0][t] + xrA[1][t] + xrA[2][t] + xrA[3][t];
        float B = xrB[0][t] + xrB[1][t] + xrB[2][t] + xrB[3][t];
        tt[r0 + t] = B / A;
    }
}

// ---------------- out = (-reg/N) * sum_i tt_i ----------------
__global__ __launch_bounds__(256) void final_loss_k(const float* __restrict__ tt,
                                                    const float* __restrict__ regbuf,
                                                    float* __restrict__ out) {
    int t = threadIdx.x;
    float s = 0.0f;
    for (int i = t; i < NN; i += 256)
        s += tt[i];
    #pragma unroll
    for (int o = 32; o; o >>= 1) s += __shfl_xor(s, o);
    __shared__ float wsum[4];
    if ((t & 63) == 0) wsum[t >> 6] = s;
    __syncthreads();
    if (t == 0)
        out[0] = -regbuf[0] * (wsum[0] + wsum[1] + wsum[2] + wsum[3]) / (float)NN;
}

extern "C" void kernel_launch(void* const* d_in, const int* in_sizes, int n_in,
                              void* d_out, int out_size, void* d_ws, size_t ws_size,
                              hipStream_t stream) {
    const float* XP = (const float*)d_in[0];
    const float* XQ = (const float*)d_in[1];
    float* out = (float*)d_out;

    // workspace layout (~130.3 MiB)
    char* p = (char*)d_ws;
    unsigned char* Kb  = (unsigned char*)p;    p += (size_t)NN * NN;          // 64 MiB
    unsigned char* KTb = (unsigned char*)p;    p += (size_t)NN * NN;          // 64 MiB
    unsigned short* XPb = (unsigned short*)p;  p += (size_t)NN * DD * 2;      // 1 MiB
    unsigned short* XQb = (unsigned short*)p;  p += (size_t)NN * DD * 2;      // 1 MiB
    float* pn = (float*)p;                     p += NN * 4;
    float* qn = (float*)p;                     p += NN * 4;
    float* vv = (float*)p;                     p += NN * 4;
    float* uu = (float*)p;                     p += NN * 4;
    float* tt = (float*)p;                     p += NN * 4;
    float* bm = (float*)p;                     p += 4096 * 4;
    float* regbuf = (float*)p;

    prep_k<<<4096, 256, 0, stream>>>(XP, XQ, XPb, XQb, pn, qn);
    gemm_max_k<<<dim3(64, 64), 256, 0, stream>>>(XPb, XQb, pn, qn, bm);
    max_red_k<<<1, 256, 0, stream>>>(bm, regbuf);
    gemm_K_k<<<dim3(64, 64), 256, 0, stream>>>(XPb, XQb, pn, qn, regbuf, Kb, KTb); // K + KT in one pass

    // v1 = (1/N)/(K^T u0), u0 = 1/N
    mv_k<<<1024, 512, 0, stream>>>(KTb, vv, vv, 1);
    for (int it = 1; it < NITER; ++it) {
        mv_k<<<1024, 512, 0, stream>>>(Kb, vv, uu, 0);    // u_it = (1/N)/(K v_it)
        mv_k<<<1024, 512, 0, stream>>>(KTb, uu, vv, 0);   // v_{it+1} = (1/N)/(K^T u_it)
    }
    loss_k<<<512, 256, 0, stream>>>(Kb, vv, tt);
    final_loss_k<<<1, 256, 0, stream>>>(tt, regbuf, out);
}

// Round 16
// 506.582 us; speedup vs baseline: 1.8670x; 1.2197x over previous
//
#include <hip/hip_runtime.h>
#include <hip/hip_bf16.h>
#include <math.h>

// EnvelopeWassersteinLoss: n=m=8192, d=64, EPS=0.05, 20 Sinkhorn iterations.
//   prep:     XP,XQ f32 -> bf16 + row sq-norms
//   gemm_max: MFMA GEMM -> per-block max -> bm[]; per-(colchunk,row) min -> rminpart
//   max_red:  bm[4096] -> regbuf {reg, inv_reg}
//   scale2:   rminpart -> mnrow[i] (exact row min of C); uu0[i] = exp(-mn/reg)/N
//   gemm_K:   GEMM; 4-BIT code nib = round((C - mn_i)/(reg*ln2)) in [0,15]
//             decode Ks = 2^-nib = as_float(0x3F800000 - nib<<23)  (shift+sub)
//             C~ = mn_i + nib*reg*ln2 EXACTLY. One pass writes Ks (32MB) + KsT.
//   loop:     row-gather matvecs on 4-bit codes; per-row scale rs_i cancels:
//             u' = (1/N)/(Ks v)  [u' = rs*u],  v = (1/N)/(KsT u')
//             iter 0: v1 = (1/N)/(KsT uu0), uu0 = rs/N from scale2.
//   loss:     SA_i = sum Ks v, SB_i = sum nib*Ks*v -> tt_i = SB/SA
//   final:    out = (1/N) * sum_i (mn_i + reg*ln2*tt_i)

#define NN 8192
#define DD 64
#define EPSV 0.05f
#define NITER 20
#define LN2F 0.69314718056f
#define INVLN2F 1.44269504089f

typedef __attribute__((ext_vector_type(8))) short short8;            // 8 x bf16
typedef __attribute__((ext_vector_type(4))) float fx4;

__device__ inline unsigned short f2bf(float f) {
    union { float f; unsigned int i; } x; x.f = f;
    unsigned int r = x.i + 0x7fffu + ((x.i >> 16) & 1u);
    return (unsigned short)(r >> 16);
}
// 4-bit decode: Ks = 2^-nib
__device__ inline float decN(unsigned int nib) {
    return __uint_as_float(0x3F800000u - (nib << 23));
}
// 8 nibbles of one word dotted with 8 v values (2 chains)
__device__ inline void dec8_dot(unsigned int x, fx4 va, fx4 vb, float& a0, float& a1) {
    a0 += decN(x & 15u) * va[0];
    a1 += decN((x >> 4) & 15u) * va[1];
    a0 += decN((x >> 8) & 15u) * va[2];
    a1 += decN((x >> 12) & 15u) * va[3];
    a0 += decN((x >> 16) & 15u) * vb[0];
    a1 += decN((x >> 20) & 15u) * vb[1];
    a0 += decN((x >> 24) & 15u) * vb[2];
    a1 += decN(x >> 28) * vb[3];
}
// loss: SA += Ks v, SB += nib*Ks*v
__device__ inline void dec8_loss(unsigned int x, fx4 va, fx4 vb, float& sa, float& sb) {
    #pragma unroll
    for (int k = 0; k < 8; ++k) {
        unsigned int nib = (x >> (4 * k)) & 15u;
        float g = decN(nib);
        float v = (k < 4) ? va[k] : vb[k - 4];
        float gv = g * v;
        sa += gv;
        sb += (float)nib * gv;
    }
}
// pack 8 code bytes (each 0..15) from two dwords into one dword of 8 nibs
__device__ inline unsigned int pack8(unsigned int lo, unsigned int hi) {
    unsigned int a = lo & 0x0F0F0F0Fu;
    a = (a | (a >> 4)) & 0x00FF00FFu;
    a = (a | (a >> 8)) & 0x0000FFFFu;
    unsigned int b = hi & 0x0F0F0F0Fu;
    b = (b | (b >> 4)) & 0x00FF00FFu;
    b = (b | (b >> 8)) & 0x0000FFFFu;
    return a | (b << 16);
}

// ---------------- prep: convert + row norms ----------------
__global__ __launch_bounds__(256) void prep_k(const float* __restrict__ XP,
                                              const float* __restrict__ XQ,
                                              unsigned short* __restrict__ XPb,
                                              unsigned short* __restrict__ XQb,
                                              float* __restrict__ pn,
                                              float* __restrict__ qn) {
    int task = blockIdx.x * 4 + (threadIdx.x >> 6);
    int lane = threadIdx.x & 63;
    const float* src; unsigned short* dst; float* nrm; int row;
    if (task < NN) { src = XP; dst = XPb; nrm = pn; row = task; }
    else           { src = XQ; dst = XQb; nrm = qn; row = task - NN; }
    float xv = src[row * DD + lane];
    dst[row * DD + lane] = f2bf(xv);
    float s = xv * xv;
    #pragma unroll
    for (int o = 32; o; o >>= 1) s += __shfl_xor(s, o);
    if (lane == 0) nrm[row] = s;
}

// ---------------- shared GEMM tile: wave computes 64x64 via 4x4 MFMA frags ----------------
__device__ inline void gemm_tile(const unsigned short* __restrict__ XPb,
                                 const unsigned short* __restrict__ XQb,
                                 int R0, int C0, int lane, fx4 acc[4][4]) {
    int r  = lane & 15;
    int ko = (lane >> 4) * 8;
    #pragma unroll
    for (int kk = 0; kk < DD; kk += 32) {
        short8 a[4], b[4];
        #pragma unroll
        for (int m = 0; m < 4; m++)
            a[m] = *(const short8*)(XPb + (R0 + m * 16 + r) * DD + kk + ko);
        #pragma unroll
        for (int n = 0; n < 4; n++)
            b[n] = *(const short8*)(XQb + (C0 + n * 16 + r) * DD + kk + ko);
        #pragma unroll
        for (int m = 0; m < 4; m++)
            #pragma unroll
            for (int n = 0; n < 4; n++)
                acc[m][n] = __builtin_amdgcn_mfma_f32_16x16x32_bf16(a[m], b[n], acc[m][n], 0, 0, 0);
    }
}

// ---------------- pass 1: per-block max -> bm[]; per-(cchunk,row) min -> rminpart ----------------
__global__ __launch_bounds__(256) void gemm_max_k(const unsigned short* __restrict__ XPb,
                                                  const unsigned short* __restrict__ XQb,
                                                  const float* __restrict__ pn,
                                                  const float* __restrict__ qn,
                                                  float* __restrict__ bm,
                                                  float* __restrict__ rminpart) {
    int w = threadIdx.x >> 6, wr = w >> 1, wc = w & 1;
    int lane = threadIdx.x & 63;
    int R0 = blockIdx.y * 128 + wr * 64;
    int C0 = blockIdx.x * 128 + wc * 64;
    fx4 acc[4][4] = {};
    gemm_tile(XPb, XQb, R0, C0, lane, acc);

    float pl = pn[R0 + lane], ql = qn[C0 + lane];
    float pr[16], qc[4];
    #pragma unroll
    for (int m = 0; m < 4; m++)
        #pragma unroll
        for (int j = 0; j < 4; j++)
            pr[m * 4 + j] = __shfl(pl, m * 16 + ((lane >> 4) << 2) + j);
    #pragma unroll
    for (int n = 0; n < 4; n++) qc[n] = __shfl(ql, n * 16 + (lane & 15));

    float mx = 0.0f;
    float mn[16];
    #pragma unroll
    for (int m = 0; m < 4; m++) {
        #pragma unroll
        for (int j = 0; j < 4; j++) {
            float lmn = 1e30f;
            #pragma unroll
            for (int n = 0; n < 4; n++) {
                float c = fmaxf(pr[m * 4 + j] + qc[n] - 2.0f * acc[m][n][j], 0.0f);
                mx = fmaxf(mx, c);
                lmn = fminf(lmn, c);
            }
            mn[m * 4 + j] = lmn;
        }
    }
    // per-row min across the 16 lanes sharing this hi-group (same rows, different col-groups)
    #pragma unroll
    for (int o = 1; o < 16; o <<= 1) {
        #pragma unroll
        for (int e = 0; e < 16; e++) mn[e] = fminf(mn[e], __shfl_xor(mn[e], o));
    }
    if ((lane & 15) == 0) {
        int hi = lane >> 4;
        int cchunk = blockIdx.x * 2 + wc;      // 128 chunks of 64 cols
        #pragma unroll
        for (int m = 0; m < 4; m++)
            #pragma unroll
            for (int j = 0; j < 4; j++)
                rminpart[(size_t)cchunk * NN + blockIdx.y * 128 + wr * 64 + m * 16 + hi * 4 + j]
                    = mn[m * 4 + j];
    }

    #pragma unroll
    for (int o = 32; o; o >>= 1) mx = fmaxf(mx, __shfl_xor(mx, o));
    __shared__ float wmax[4];
    if (lane == 0) wmax[w] = mx;
    __syncthreads();
    if (threadIdx.x == 0)
        bm[blockIdx.y * 64 + blockIdx.x] = fmaxf(fmaxf(wmax[0], wmax[1]), fmaxf(wmax[2], wmax[3]));
}

// ---------------- reduce bm[4096] -> regbuf {reg, inv_reg} ----------------
__global__ __launch_bounds__(256) void max_red_k(const float* __restrict__ bm,
                                                 float* __restrict__ regbuf) {
    int t = threadIdx.x;
    float mx = 0.0f;
    #pragma unroll
    for (int i = 0; i < 16; ++i) mx = fmaxf(mx, bm[i * 256 + t]);
    #pragma unroll
    for (int o = 32; o; o >>= 1) mx = fmaxf(mx, __shfl_xor(mx, o));
    __shared__ float wmax[4];
    if ((t & 63) == 0) wmax[t >> 6] = mx;
    __syncthreads();
    if (t == 0) {
        float m = fmaxf(fmaxf(wmax[0], wmax[1]), fmaxf(wmax[2], wmax[3]));
        float reg = EPSV * m;
        regbuf[0] = reg;
        regbuf[1] = 1.0f / reg;
    }
}

// ---------------- per-row min + u'0 = exp(-mn/reg)/N ----------------
__global__ __launch_bounds__(256) void scale2_k(const float* __restrict__ rminpart,
                                                const float* __restrict__ regbuf,
                                                float* __restrict__ mnrow,
                                                float* __restrict__ uu0) {
    int row = blockIdx.x * 256 + threadIdx.x;
    float mn = 1e30f;
    #pragma unroll 8
    for (int c = 0; c < 128; ++c) mn = fminf(mn, rminpart[(size_t)c * NN + row]);
    mnrow[row] = mn;
    uu0[row] = __expf(-mn * regbuf[1]) / (float)NN;
}

// ---------------- pass 2: 4-bit codes; ONE pass stores BOTH Ks and KsT ----------------
__global__ __launch_bounds__(256) void gemm_K_k(const unsigned short* __restrict__ XPb,
                                                const unsigned short* __restrict__ XQb,
                                                const float* __restrict__ pn,
                                                const float* __restrict__ qn,
                                                const float* __restrict__ regbuf,
                                                const float* __restrict__ mnrow,
                                                unsigned char* __restrict__ Kb4,
                                                unsigned char* __restrict__ KTb4) {
    __shared__ unsigned char tile[128][136];
    __shared__ unsigned char tileT[128][136];
    int w = threadIdx.x >> 6, wr = w >> 1, wc = w & 1;
    int lane = threadIdx.x & 63;
    int R0 = blockIdx.y * 128 + wr * 64;
    int C0 = blockIdx.x * 128 + wc * 64;
    fx4 acc[4][4] = {};
    gemm_tile(XPb, XQb, R0, C0, lane, acc);

    float k1 = regbuf[1] * INVLN2F;            // codes per C-unit = 1/(reg*ln2)
    float pl = pn[R0 + lane], ql = qn[C0 + lane];
    float mnl = mnrow[R0 + lane];
    float pr[16], qc[4], mnr[16];
    #pragma unroll
    for (int m = 0; m < 4; m++)
        #pragma unroll
        for (int j = 0; j < 4; j++) {
            int src = m * 16 + ((lane >> 4) << 2) + j;
            pr[m * 4 + j]  = __shfl(pl, src);
            mnr[m * 4 + j] = __shfl(mnl, src);
        }
    #pragma unroll
    for (int n = 0; n < 4; n++) qc[n] = __shfl(ql, n * 16 + (lane & 15));

    #pragma unroll
    for (int m = 0; m < 4; m++) {
        #pragma unroll
        for (int n = 0; n < 4; n++) {
            #pragma unroll
            for (int j = 0; j < 4; j++) {
                float c = fmaxf(pr[m * 4 + j] + qc[n] - 2.0f * acc[m][n][j], 0.0f);
                int L = (int)(fmaf(c - mnr[m * 4 + j], k1, 0.5f));
                L = L < 0 ? 0 : (L > 15 ? 15 : L);
                int lr = wr * 64 + m * 16 + ((lane >> 4) << 2) + j;
                int lc = wc * 64 + n * 16 + (lane & 15);
                tile[lr][lc]  = (unsigned char)L;
                tileT[lc][lr] = (unsigned char)L;
            }
        }
    }
    __syncthreads();

    // pack 8 code bytes -> 1 dword of nibs; 16 lanes x 4B = 64B per tile row
    int lane16 = threadIdx.x & 15;
    int rowgrp = threadIdx.x >> 4;
    size_t Rg = (size_t)blockIdx.y * 128;
    size_t Cg = (size_t)blockIdx.x * 128;
    #pragma unroll
    for (int s = 0; s < 8; ++s) {
        int row = s * 16 + rowgrp;
        uint2 pk = *(const uint2*)&tile[row][lane16 * 8];
        *(unsigned int*)(Kb4 + (Rg + row) * (NN / 2) + (Cg >> 1) + lane16 * 4) = pack8(pk.x, pk.y);
        uint2 pt = *(const uint2*)&tileT[row][lane16 * 8];
        *(unsigned int*)(KTb4 + (Cg + row) * (NN / 2) + (Rg >> 1) + lane16 * 4) = pack8(pt.x, pt.y);
    }
}

// ---------------- row-gather matvec, 4-bit: wout = (1/N)/(M win) ----------------
// block = 8 rows x 256 thr (4 waves). Lane owns 32 contiguous cols (16B codes).
// codes: 8 x uint4 issued up front; v: 8 x fx4 from global (L2 broadcast).
__global__ __launch_bounds__(256) void mv_k(const unsigned char* __restrict__ M4,
                                            const float* __restrict__ win,
                                            float* __restrict__ wout) {
    __shared__ float xp[4 * 8 * 64];   // [wave][row][lane] = 8 KiB
    int t = threadIdx.x;
    int w = t >> 6, l = t & 63;
    int row0 = blockIdx.x << 3;
    int cb = (w << 11) + (l << 5);                    // 32 cols per lane
    const unsigned char* Mp = M4 + (size_t)row0 * (NN / 2) + (cb >> 1);

    uint4 cw[8];
    #pragma unroll
    for (int r = 0; r < 8; ++r)
        cw[r] = *(const uint4*)(Mp + (size_t)r * (NN / 2));

    fx4 vr[8];
    #pragma unroll
    for (int q = 0; q < 8; ++q)
        vr[q] = *(const fx4*)(win + cb + q * 4);

    #pragma unroll
    for (int r = 0; r < 8; ++r) {
        float a0 = 0.0f, a1 = 0.0f;
        dec8_dot(cw[r].x, vr[0], vr[1], a0, a1);
        dec8_dot(cw[r].y, vr[2], vr[3], a0, a1);
        dec8_dot(cw[r].z, vr[4], vr[5], a0, a1);
        dec8_dot(cw[r].w, vr[6], vr[7], a0, a1);
        xp[(w << 9) + (r << 6) + l] = a0 + a1;
    }
    __syncthreads();

    // 8 rows over 4 waves: wave w reduces rows 2w, 2w+1
    #pragma unroll
    for (int k = 0; k < 2; ++k) {
        int rr = (w << 1) + k;
        float s = 0.0f;
        #pragma unroll
        for (int q = 0; q < 4; ++q)
            s += xp[(q << 9) + (rr << 6) + l];
        #pragma unroll
        for (int o = 32; o; o >>= 1) s += __shfl_xor(s, o);
        if (l == 0) wout[row0 + rr] = (1.0f / (float)NN) / s;
    }
}

// ---------------- loss pass: SA = sum Ks v, SB = sum nib*Ks*v -> tt = SB/SA ----------------
__global__ __launch_bounds__(256) void loss_k(const unsigned char* __restrict__ Kb4,
                                              const float* __restrict__ vv,
                                              float* __restrict__ tt) {
    __shared__ float xrA[4][16];
    __shared__ float xrB[4][16];
    int t = threadIdx.x;
    int w = t >> 6, l = t & 63;
    size_t r0 = (size_t)blockIdx.x * 16;
    int cb = (w << 11) + (l << 5);
    fx4 vr[8];
    #pragma unroll
    for (int q = 0; q < 8; ++q)
        vr[q] = *(const fx4*)(vv + cb + q * 4);

    #pragma unroll
    for (int i = 0; i < 16; ++i) {
        float sa = 0.0f, sb = 0.0f;
        uint4 q = *(const uint4*)(Kb4 + (r0 + i) * (NN / 2) + (cb >> 1));
        dec8_loss(q.x, vr[0], vr[1], sa, sb);
        dec8_loss(q.y, vr[2], vr[3], sa, sb);
        dec8_loss(q.z, vr[4], vr[5], sa, sb);
        dec8_loss(q.w, vr[6], vr[7], sa, sb);
        #pragma unroll
        for (int o = 32; o; o >>= 1) {
            sa += __shfl_xor(sa, o);
            sb += __shfl_xor(sb, o);
        }
        if (l == 0) { xrA[w][i] = sa; xrB[w][i] = sb; }
    }
    __syncthreads();
    if (t < 16) {
        float A = xrA[0][t] + xrA[1][t] + xrA[2][t] + xrA[3][t];
        float B = xrB[0][t] + xrB[1][t] + xrB[2][t] + xrB[3][t];
        tt[r0 + t] = B / A;
    }
}

// ---------------- out = (1/N) * sum_i (mn_i + reg*ln2*tt_i) ----------------
__global__ __launch_bounds__(256) void final_loss_k(const float* __restrict__ mnrow,
                                                    const float* __restrict__ tt,
                                                    const float* __restrict__ regbuf,
                                                    float* __restrict__ out) {
    int t = threadIdx.x;
    float c1 = regbuf[0] * LN2F;
    float s = 0.0f;
    for (int i = t; i < NN; i += 256)
        s += mnrow[i] + c1 * tt[i];
    #pragma unroll
    for (int o = 32; o; o >>= 1) s += __shfl_xor(s, o);
    __shared__ float wsum[4];
    if ((t & 63) == 0) wsum[t >> 6] = s;
    __syncthreads();
    if (t == 0)
        out[0] = (wsum[0] + wsum[1] + wsum[2] + wsum[3]) / (float)NN;
}

extern "C" void kernel_launch(void* const* d_in, const int* in_sizes, int n_in,
                              void* d_out, int out_size, void* d_ws, size_t ws_size,
                              hipStream_t stream) {
    const float* XP = (const float*)d_in[0];
    const float* XQ = (const float*)d_in[1];
    float* out = (float*)d_out;

    // workspace layout (~72.5 MiB)
    char* p = (char*)d_ws;
    unsigned char* Kb4  = (unsigned char*)p;   p += (size_t)NN * NN / 2;      // 32 MiB
    unsigned char* KTb4 = (unsigned char*)p;   p += (size_t)NN * NN / 2;      // 32 MiB
    unsigned short* XPb = (unsigned short*)p;  p += (size_t)NN * DD * 2;      // 1 MiB
    unsigned short* XQb = (unsigned short*)p;  p += (size_t)NN * DD * 2;      // 1 MiB
    float* rminpart = (float*)p;               p += (size_t)128 * NN * 4;     // 4 MiB
    float* pn = (float*)p;                     p += NN * 4;
    float* qn = (float*)p;                     p += NN * 4;
    float* vv = (float*)p;                     p += NN * 4;
    float* uu = (float*)p;                     p += NN * 4;
    float* tt = (float*)p;                     p += NN * 4;
    float* mnrow = (float*)p;                  p += NN * 4;
    float* bm = (float*)p;                     p += 4096 * 4;
    float* regbuf = (float*)p;

    prep_k<<<4096, 256, 0, stream>>>(XP, XQ, XPb, XQb, pn, qn);
    gemm_max_k<<<dim3(64, 64), 256, 0, stream>>>(XPb, XQb, pn, qn, bm, rminpart);
    max_red_k<<<1, 256, 0, stream>>>(bm, regbuf);
    scale2_k<<<32, 256, 0, stream>>>(rminpart, regbuf, mnrow, uu);   // mnrow + u'0 in uu
    gemm_K_k<<<dim3(64, 64), 256, 0, stream>>>(XPb, XQb, pn, qn, regbuf, mnrow, Kb4, KTb4);

    // v1 = (1/N)/(KsT u'0)
    mv_k<<<1024, 256, 0, stream>>>(KTb4, uu, vv);
    for (int it = 1; it < NITER; ++it) {
        mv_k<<<1024, 256, 0, stream>>>(Kb4, vv, uu);    // u' = (1/N)/(Ks v)
        mv_k<<<1024, 256, 0, stream>>>(KTb4, uu, vv);   // v  = (1/N)/(KsT u')
    }
    loss_k<<<512, 256, 0, stream>>>(Kb4, vv, tt);
    final_loss_k<<<1, 256, 0, stream>>>(mnrow, tt, regbuf, out);
}

// Round 17
// 491.584 us; speedup vs baseline: 1.9239x; 1.0305x over previous
//
#include <hip/hip_runtime.h>
#include <hip/hip_bf16.h>
#include <math.h>

// EnvelopeWassersteinLoss: n=m=8192, d=64, EPS=0.05, 20 Sinkhorn iterations.
//   prep:     XP,XQ f32 -> bf16 + row sq-norms
//   gemm_max: LDS-staged MFMA GEMM -> per-block max -> bm[]; per-(cchunk,row) min -> rminpart
//   max_red:  bm[4096] -> regbuf {reg, inv_reg}
//   scale2:   rminpart -> mnrow[i] (exact row min of C); uu0[i] = exp(-mn/reg)/N
//   gemm_K:   LDS-staged GEMM; 4-BIT code nib = round((C - mn_i)/(reg*ln2)) in [0,15]
//             decode Ks = 2^-nib = as_float(0x3F800000 - nib<<23)  (shift+sub)
//             C~ = mn_i + nib*reg*ln2 EXACTLY. One pass writes Ks (32MB) + KsT.
//   loop:     row-gather matvecs on 4-bit codes; per-row scale rs_i cancels:
//             u' = (1/N)/(Ks v),  v = (1/N)/(KsT u'); iter 0 uses uu0 = rs/N.
//   loss:     SA_i = sum Ks v, SB_i = sum nib*Ks*v -> tt_i = SB/SA
//   final:    out = (1/N) * sum_i (mn_i + reg*ln2*tt_i)

#define NN 8192
#define DD 64
#define EPSV 0.05f
#define NITER 20
#define LN2F 0.69314718056f
#define INVLN2F 1.44269504089f

typedef __attribute__((ext_vector_type(8))) short short8;            // 8 x bf16
typedef __attribute__((ext_vector_type(4))) float fx4;

__device__ inline unsigned short f2bf(float f) {
    union { float f; unsigned int i; } x; x.f = f;
    unsigned int r = x.i + 0x7fffu + ((x.i >> 16) & 1u);
    return (unsigned short)(r >> 16);
}
// 4-bit decode: Ks = 2^-nib
__device__ inline float decN(unsigned int nib) {
    return __uint_as_float(0x3F800000u - (nib << 23));
}
// 8 nibbles of one word dotted with 8 v values (2 chains)
__device__ inline void dec8_dot(unsigned int x, fx4 va, fx4 vb, float& a0, float& a1) {
    a0 += decN(x & 15u) * va[0];
    a1 += decN((x >> 4) & 15u) * va[1];
    a0 += decN((x >> 8) & 15u) * va[2];
    a1 += decN((x >> 12) & 15u) * va[3];
    a0 += decN((x >> 16) & 15u) * vb[0];
    a1 += decN((x >> 20) & 15u) * vb[1];
    a0 += decN((x >> 24) & 15u) * vb[2];
    a1 += decN(x >> 28) * vb[3];
}
// loss: SA += Ks v, SB += nib*Ks*v
__device__ inline void dec8_loss(unsigned int x, fx4 va, fx4 vb, float& sa, float& sb) {
    #pragma unroll
    for (int k = 0; k < 8; ++k) {
        unsigned int nib = (x >> (4 * k)) & 15u;
        float g = decN(nib);
        float v = (k < 4) ? va[k] : vb[k - 4];
        float gv = g * v;
        sa += gv;
        sb += (float)nib * gv;
    }
}
// pack 8 code bytes (each 0..15) from two dwords into one dword of 8 nibs
__device__ inline unsigned int pack8(unsigned int lo, unsigned int hi) {
    unsigned int a = lo & 0x0F0F0F0Fu;
    a = (a | (a >> 4)) & 0x00FF00FFu;
    a = (a | (a >> 8)) & 0x0000FFFFu;
    unsigned int b = hi & 0x0F0F0F0Fu;
    b = (b | (b >> 4)) & 0x00FF00FFu;
    b = (b | (b >> 8)) & 0x0000FFFFu;
    return a | (b << 16);
}

// ---------------- prep: convert + row norms ----------------
__global__ __launch_bounds__(256) void prep_k(const float* __restrict__ XP,
                                              const float* __restrict__ XQ,
                                              unsigned short* __restrict__ XPb,
                                              unsigned short* __restrict__ XQb,
                                              float* __restrict__ pn,
                                              float* __restrict__ qn) {
    int task = blockIdx.x * 4 + (threadIdx.x >> 6);
    int lane = threadIdx.x & 63;
    const float* src; unsigned short* dst; float* nrm; int row;
    if (task < NN) { src = XP; dst = XPb; nrm = pn; row = task; }
    else           { src = XQ; dst = XQb; nrm = qn; row = task - NN; }
    float xv = src[row * DD + lane];
    dst[row * DD + lane] = f2bf(xv);
    float s = xv * xv;
    #pragma unroll
    for (int o = 32; o; o >>= 1) s += __shfl_xor(s, o);
    if (lane == 0) nrm[row] = s;
}

// ---------------- LDS-staged GEMM tile ----------------
// Block tile 128x128. A-tile = 128 contiguous rows of XPb (16 KB), B-tile
// likewise from XQb. Staged with coalesced uint4 loads + XOR-swizzled
// ds_writes (slot = cc ^ (row&7)) so fragment ds_read_b128s are ~2-way.
// Wave (wr,wc) computes its 64x64 via 4x4 MFMA frags — inputs bit-identical
// to the old direct-gather version.
__device__ inline void gemm_tile_lds(const unsigned short* __restrict__ XPb,
                                     const unsigned short* __restrict__ XQb,
                                     unsigned short* tA, unsigned short* tB,
                                     int Rblk, int Cblk, int tid,
                                     int wr, int wc, int lane, fx4 acc[4][4]) {
    const uint4* gA = (const uint4*)(XPb + (size_t)Rblk * DD);
    const uint4* gB = (const uint4*)(XQb + (size_t)Cblk * DD);
    #pragma unroll
    for (int i = 0; i < 4; ++i) {
        int c = i * 256 + tid;               // chunk 0..1023 (16B each)
        int row = c >> 3, cc = c & 7;
        int dst = row * 64 + ((cc ^ (row & 7)) << 3);
        uint4 va = gA[c];
        uint4 vb = gB[c];
        *(uint4*)(tA + dst) = va;
        *(uint4*)(tB + dst) = vb;
    }
    __syncthreads();

    int r  = lane & 15;
    int hi = lane >> 4;
    #pragma unroll
    for (int kk = 0; kk < DD; kk += 32) {
        int cbase = (kk >> 3) + hi;          // original 16B-chunk index
        short8 a[4], b[4];
        #pragma unroll
        for (int m = 0; m < 4; m++) {
            int row = wr * 64 + m * 16 + r;
            a[m] = *(const short8*)(tA + row * 64 + ((cbase ^ (row & 7)) << 3));
        }
        #pragma unroll
        for (int n = 0; n < 4; n++) {
            int row = wc * 64 + n * 16 + r;
            b[n] = *(const short8*)(tB + row * 64 + ((cbase ^ (row & 7)) << 3));
        }
        #pragma unroll
        for (int m = 0; m < 4; m++)
            #pragma unroll
            for (int n = 0; n < 4; n++)
                acc[m][n] = __builtin_amdgcn_mfma_f32_16x16x32_bf16(a[m], b[n], acc[m][n], 0, 0, 0);
    }
}

// ---------------- pass 1: per-block max -> bm[]; per-(cchunk,row) min -> rminpart ----------------
__global__ __launch_bounds__(256) void gemm_max_k(const unsigned short* __restrict__ XPb,
                                                  const unsigned short* __restrict__ XQb,
                                                  const float* __restrict__ pn,
                                                  const float* __restrict__ qn,
                                                  float* __restrict__ bm,
                                                  float* __restrict__ rminpart) {
    __shared__ unsigned short tA[128 * 64];
    __shared__ unsigned short tB[128 * 64];
    int w = threadIdx.x >> 6, wr = w >> 1, wc = w & 1;
    int lane = threadIdx.x & 63;
    int R0 = blockIdx.y * 128 + wr * 64;
    int C0 = blockIdx.x * 128 + wc * 64;
    fx4 acc[4][4] = {};
    gemm_tile_lds(XPb, XQb, tA, tB, blockIdx.y * 128, blockIdx.x * 128,
                  threadIdx.x, wr, wc, lane, acc);

    float pl = pn[R0 + lane], ql = qn[C0 + lane];
    float pr[16], qc[4];
    #pragma unroll
    for (int m = 0; m < 4; m++)
        #pragma unroll
        for (int j = 0; j < 4; j++)
            pr[m * 4 + j] = __shfl(pl, m * 16 + ((lane >> 4) << 2) + j);
    #pragma unroll
    for (int n = 0; n < 4; n++) qc[n] = __shfl(ql, n * 16 + (lane & 15));

    float mx = 0.0f;
    float mn[16];
    #pragma unroll
    for (int m = 0; m < 4; m++) {
        #pragma unroll
        for (int j = 0; j < 4; j++) {
            float lmn = 1e30f;
            #pragma unroll
            for (int n = 0; n < 4; n++) {
                float c = fmaxf(pr[m * 4 + j] + qc[n] - 2.0f * acc[m][n][j], 0.0f);
                mx = fmaxf(mx, c);
                lmn = fminf(lmn, c);
            }
            mn[m * 4 + j] = lmn;
        }
    }
    // per-row min across the 16 lanes sharing this hi-group
    #pragma unroll
    for (int o = 1; o < 16; o <<= 1) {
        #pragma unroll
        for (int e = 0; e < 16; e++) mn[e] = fminf(mn[e], __shfl_xor(mn[e], o));
    }
    if ((lane & 15) == 0) {
        int hi = lane >> 4;
        int cchunk = blockIdx.x * 2 + wc;
        #pragma unroll
        for (int m = 0; m < 4; m++)
            #pragma unroll
            for (int j = 0; j < 4; j++)
                rminpart[(size_t)cchunk * NN + blockIdx.y * 128 + wr * 64 + m * 16 + hi * 4 + j]
                    = mn[m * 4 + j];
    }

    #pragma unroll
    for (int o = 32; o; o >>= 1) mx = fmaxf(mx, __shfl_xor(mx, o));
    __shared__ float wmax[4];
    if (lane == 0) wmax[w] = mx;
    __syncthreads();
    if (threadIdx.x == 0)
        bm[blockIdx.y * 64 + blockIdx.x] = fmaxf(fmaxf(wmax[0], wmax[1]), fmaxf(wmax[2], wmax[3]));
}

// ---------------- reduce bm[4096] -> regbuf {reg, inv_reg} ----------------
__global__ __launch_bounds__(256) void max_red_k(const float* __restrict__ bm,
                                                 float* __restrict__ regbuf) {
    int t = threadIdx.x;
    float mx = 0.0f;
    #pragma unroll
    for (int i = 0; i < 16; ++i) mx = fmaxf(mx, bm[i * 256 + t]);
    #pragma unroll
    for (int o = 32; o; o >>= 1) mx = fmaxf(mx, __shfl_xor(mx, o));
    __shared__ float wmax[4];
    if ((t & 63) == 0) wmax[t >> 6] = mx;
    __syncthreads();
    if (t == 0) {
        float m = fmaxf(fmaxf(wmax[0], wmax[1]), fmaxf(wmax[2], wmax[3]));
        float reg = EPSV * m;
        regbuf[0] = reg;
        regbuf[1] = 1.0f / reg;
    }
}

// ---------------- per-row min + u'0 = exp(-mn/reg)/N ----------------
__global__ __launch_bounds__(256) void scale2_k(const float* __restrict__ rminpart,
                                                const float* __restrict__ regbuf,
                                                float* __restrict__ mnrow,
                                                float* __restrict__ uu0) {
    int row = blockIdx.x * 256 + threadIdx.x;
    float mn = 1e30f;
    #pragma unroll 8
    for (int c = 0; c < 128; ++c) mn = fminf(mn, rminpart[(size_t)c * NN + row]);
    mnrow[row] = mn;
    uu0[row] = __expf(-mn * regbuf[1]) / (float)NN;
}

// ---------------- pass 2: 4-bit codes; ONE pass stores BOTH Ks and KsT ----------------
__global__ __launch_bounds__(256) void gemm_K_k(const unsigned short* __restrict__ XPb,
                                                const unsigned short* __restrict__ XQb,
                                                const float* __restrict__ pn,
                                                const float* __restrict__ qn,
                                                const float* __restrict__ regbuf,
                                                const float* __restrict__ mnrow,
                                                unsigned char* __restrict__ Kb4,
                                                unsigned char* __restrict__ KTb4) {
    __shared__ unsigned short tA[128 * 64];     // 16 KiB (reused as nothing else)
    __shared__ unsigned short tB[128 * 64];     // 16 KiB
    __shared__ unsigned char tile[128][136];
    __shared__ unsigned char tileT[128][136];
    int w = threadIdx.x >> 6, wr = w >> 1, wc = w & 1;
    int lane = threadIdx.x & 63;
    int R0 = blockIdx.y * 128 + wr * 64;
    int C0 = blockIdx.x * 128 + wc * 64;
    fx4 acc[4][4] = {};
    gemm_tile_lds(XPb, XQb, tA, tB, blockIdx.y * 128, blockIdx.x * 128,
                  threadIdx.x, wr, wc, lane, acc);

    float k1 = regbuf[1] * INVLN2F;            // codes per C-unit = 1/(reg*ln2)
    float pl = pn[R0 + lane], ql = qn[C0 + lane];
    float mnl = mnrow[R0 + lane];
    float pr[16], qc[4], mnr[16];
    #pragma unroll
    for (int m = 0; m < 4; m++)
        #pragma unroll
        for (int j = 0; j < 4; j++) {
            int src = m * 16 + ((lane >> 4) << 2) + j;
            pr[m * 4 + j]  = __shfl(pl, src);
            mnr[m * 4 + j] = __shfl(mnl, src);
        }
    #pragma unroll
    for (int n = 0; n < 4; n++) qc[n] = __shfl(ql, n * 16 + (lane & 15));

    #pragma unroll
    for (int m = 0; m < 4; m++) {
        #pragma unroll
        for (int n = 0; n < 4; n++) {
            #pragma unroll
            for (int j = 0; j < 4; j++) {
                float c = fmaxf(pr[m * 4 + j] + qc[n] - 2.0f * acc[m][n][j], 0.0f);
                int L = (int)(fmaf(c - mnr[m * 4 + j], k1, 0.5f));
                L = L < 0 ? 0 : (L > 15 ? 15 : L);
                int lr = wr * 64 + m * 16 + ((lane >> 4) << 2) + j;
                int lc = wc * 64 + n * 16 + (lane & 15);
                tile[lr][lc]  = (unsigned char)L;
                tileT[lc][lr] = (unsigned char)L;
            }
        }
    }
    __syncthreads();

    int lane16 = threadIdx.x & 15;
    int rowgrp = threadIdx.x >> 4;
    size_t Rg = (size_t)blockIdx.y * 128;
    size_t Cg = (size_t)blockIdx.x * 128;
    #pragma unroll
    for (int s = 0; s < 8; ++s) {
        int row = s * 16 + rowgrp;
        uint2 pk = *(const uint2*)&tile[row][lane16 * 8];
        *(unsigned int*)(Kb4 + (Rg + row) * (NN / 2) + (Cg >> 1) + lane16 * 4) = pack8(pk.x, pk.y);
        uint2 pt = *(const uint2*)&tileT[row][lane16 * 8];
        *(unsigned int*)(KTb4 + (Cg + row) * (NN / 2) + (Rg >> 1) + lane16 * 4) = pack8(pt.x, pt.y);
    }
}

// ---------------- row-gather matvec, 4-bit: wout = (1/N)/(M win) ----------------
__global__ __launch_bounds__(256) void mv_k(const unsigned char* __restrict__ M4,
                                            const float* __restrict__ win,
                                            float* __restrict__ wout) {
    __shared__ float xp[4 * 8 * 64];   // [wave][row][lane] = 8 KiB
    int t = threadIdx.x;
    int w = t >> 6, l = t & 63;
    int row0 = blockIdx.x << 3;
    int cb = (w << 11) + (l << 5);                    // 32 cols per lane
    const unsigned char* Mp = M4 + (size_t)row0 * (NN / 2) + (cb >> 1);

    uint4 cw[8];
    #pragma unroll
    for (int r = 0; r < 8; ++r)
        cw[r] = *(const uint4*)(Mp + (size_t)r * (NN / 2));

    fx4 vr[8];
    #pragma unroll
    for (int q = 0; q < 8; ++q)
        vr[q] = *(const fx4*)(win + cb + q * 4);

    #pragma unroll
    for (int r = 0; r < 8; ++r) {
        float a0 = 0.0f, a1 = 0.0f;
        dec8_dot(cw[r].x, vr[0], vr[1], a0, a1);
        dec8_dot(cw[r].y, vr[2], vr[3], a0, a1);
        dec8_dot(cw[r].z, vr[4], vr[5], a0, a1);
        dec8_dot(cw[r].w, vr[6], vr[7], a0, a1);
        xp[(w << 9) + (r << 6) + l] = a0 + a1;
    }
    __syncthreads();

    #pragma unroll
    for (int k = 0; k < 2; ++k) {
        int rr = (w << 1) + k;
        float s = 0.0f;
        #pragma unroll
        for (int q = 0; q < 4; ++q)
            s += xp[(q << 9) + (rr << 6) + l];
        #pragma unroll
        for (int o = 32; o; o >>= 1) s += __shfl_xor(s, o);
        if (l == 0) wout[row0 + rr] = (1.0f / (float)NN) / s;
    }
}

// ---------------- loss pass: SA = sum Ks v, SB = sum nib*Ks*v -> tt = SB/SA ----------------
__global__ __launch_bounds__(256) void loss_k(const unsigned char* __restrict__ Kb4,
                                              const float* __restrict__ vv,
                                              float* __restrict__ tt) {
    __shared__ float xrA[4][16];
    __shared__ float xrB[4][16];
    int t = threadIdx.x;
    int w = t >> 6, l = t & 63;
    size_t r0 = (size_t)blockIdx.x * 16;
    int cb = (w << 11) + (l << 5);
    fx4 vr[8];
    #pragma unroll
    for (int q = 0; q < 8; ++q)
        vr[q] = *(const fx4*)(vv + cb + q * 4);

    #pragma unroll
    for (int i = 0; i < 16; ++i) {
        float sa = 0.0f, sb = 0.0f;
        uint4 q = *(const uint4*)(Kb4 + (r0 + i) * (NN / 2) + (cb >> 1));
        dec8_loss(q.x, vr[0], vr[1], sa, sb);
        dec8_loss(q.y, vr[2], vr[3], sa, sb);
        dec8_loss(q.z, vr[4], vr[5], sa, sb);
        dec8_loss(q.w, vr[6], vr[7], sa, sb);
        #pragma unroll
        for (int o = 32; o; o >>= 1) {
            sa += __shfl_xor(sa, o);
            sb += __shfl_xor(sb, o);
        }
        if (l == 0) { xrA[w][i] = sa; xrB[w][i] = sb; }
    }
    __syncthreads();
    if (t < 16) {
        float A = xrA[0][t] + xrA[1][t] + xrA[2][t] + xrA[3][t];
        float B = xrB[0][t] + xrB[1][t] + xrB[2][t] + xrB[3][t];
        tt[r0 + t] = B / A;
    }
}

// ---------------- out = (1/N) * sum_i (mn_i + reg*ln2*tt_i) ----------------
__global__ __launch_bounds__(256) void final_loss_k(const float* __restrict__ mnrow,
                                                    const float* __restrict__ tt,
                                                    const float* __restrict__ regbuf,
                                                    float* __restrict__ out) {
    int t = threadIdx.x;
    float c1 = regbuf[0] * LN2F;
    float s = 0.0f;
    for (int i = t; i < NN; i += 256)
        s += mnrow[i] + c1 * tt[i];
    #pragma unroll
    for (int o = 32; o; o >>= 1) s += __shfl_xor(s, o);
    __shared__ float wsum[4];
    if ((t & 63) == 0) wsum[t >> 6] = s;
    __syncthreads();
    if (t == 0)
        out[0] = (wsum[0] + wsum[1] + wsum[2] + wsum[3]) / (float)NN;
}

extern "C" void kernel_launch(void* const* d_in, const int* in_sizes, int n_in,
                              void* d_out, int out_size, void* d_ws, size_t ws_size,
                              hipStream_t stream) {
    const float* XP = (const float*)d_in[0];
    const float* XQ = (const float*)d_in[1];
    float* out = (float*)d_out;

    // workspace layout (~72.5 MiB)
    char* p = (char*)d_ws;
    unsigned char* Kb4  = (unsigned char*)p;   p += (size_t)NN * NN / 2;      // 32 MiB
    unsigned char* KTb4 = (unsigned char*)p;   p += (size_t)NN * NN / 2;      // 32 MiB
    unsigned short* XPb = (unsigned short*)p;  p += (size_t)NN * DD * 2;      // 1 MiB
    unsigned short* XQb = (unsigned short*)p;  p += (size_t)NN * DD * 2;      // 1 MiB
    float* rminpart = (float*)p;               p += (size_t)128 * NN * 4;     // 4 MiB
    float* pn = (float*)p;                     p += NN * 4;
    float* qn = (float*)p;                     p += NN * 4;
    float* vv = (float*)p;                     p += NN * 4;
    float* uu = (float*)p;                     p += NN * 4;
    float* tt = (float*)p;                     p += NN * 4;
    float* mnrow = (float*)p;                  p += NN * 4;
    float* bm = (float*)p;                     p += 4096 * 4;
    float* regbuf = (float*)p;

    prep_k<<<4096, 256, 0, stream>>>(XP, XQ, XPb, XQb, pn, qn);
    gemm_max_k<<<dim3(64, 64), 256, 0, stream>>>(XPb, XQb, pn, qn, bm, rminpart);
    max_red_k<<<1, 256, 0, stream>>>(bm, regbuf);
    scale2_k<<<32, 256, 0, stream>>>(rminpart, regbuf, mnrow, uu);   // mnrow + u'0 in uu
    gemm_K_k<<<dim3(64, 64), 256, 0, stream>>>(XPb, XQb, pn, qn, regbuf, mnrow, Kb4, KTb4);

    // v1 = (1/N)/(KsT u'0)
    mv_k<<<1024, 256, 0, stream>>>(KTb4, uu, vv);
    for (int it = 1; it < NITER; ++it) {
        mv_k<<<1024, 256, 0, stream>>>(Kb4, vv, uu);    // u' = (1/N)/(Ks v)
        mv_k<<<1024, 256, 0, stream>>>(KTb4, uu, vv);   // v  = (1/N)/(KsT u')
    }
    loss_k<<<512, 256, 0, stream>>>(Kb4, vv, tt);
    final_loss_k<<<1, 256, 0, stream>>>(mnrow, tt, regbuf, out);
}

// Round 18
// 483.955 us; speedup vs baseline: 1.9543x; 1.0158x over previous
//
#include <hip/hip_runtime.h>
#include <hip/hip_bf16.h>
#include <math.h>

// EnvelopeWassersteinLoss: n=m=8192, d=64, EPS=0.05, 20 Sinkhorn iterations.
//   prep:     XP,XQ f32 -> bf16 + row sq-norms
//   gemm_max: LDS-staged MFMA GEMM -> per-block max -> bm[]; per-(cchunk,row) min -> rminpart
//   max_red:  bm[4096] -> regbuf {reg, inv_reg}
//   scale2:   rminpart -> mnrow[i] (exact row min of C); uu0[i] = exp(-mn/reg)/N
//   gemm_K:   LDS-staged GEMM; 4-BIT code nib = round((C - mn_i)/(reg*ln2)) in [0,15]
//             decode Ks = 2^-nib = as_float(0x3F800000 - nib<<23)  (shift+sub)
//             C~ = mn_i + nib*reg*ln2 EXACTLY. One pass writes Ks (32MB) + KsT.
//   loop:     row-gather matvecs on 4-bit codes; per-row scale rs_i cancels:
//             u' = (1/N)/(Ks v),  v = (1/N)/(KsT u'); iter 0 uses uu0 = rs/N.
//             mv v3: 16 rows/block (grid 512) halves the per-pass v-broadcast
//             traffic (each block reads full v once); codes in 2 batches of 8
//             rows; lane owns 16 contiguous cols (8B codes, coalesced).
//   loss:     SA_i = sum Ks v, SB_i = sum nib*Ks*v -> tt_i = SB/SA
//   final:    out = (1/N) * sum_i (mn_i + reg*ln2*tt_i)

#define NN 8192
#define DD 64
#define EPSV 0.05f
#define NITER 20
#define LN2F 0.69314718056f
#define INVLN2F 1.44269504089f

typedef __attribute__((ext_vector_type(8))) short short8;            // 8 x bf16
typedef __attribute__((ext_vector_type(4))) float fx4;

__device__ inline unsigned short f2bf(float f) {
    union { float f; unsigned int i; } x; x.f = f;
    unsigned int r = x.i + 0x7fffu + ((x.i >> 16) & 1u);
    return (unsigned short)(r >> 16);
}
// 4-bit decode: Ks = 2^-nib
__device__ inline float decN(unsigned int nib) {
    return __uint_as_float(0x3F800000u - (nib << 23));
}
// 8 nibbles of one word dotted with 8 v values (2 chains)
__device__ inline void dec8_dot(unsigned int x, fx4 va, fx4 vb, float& a0, float& a1) {
    a0 += decN(x & 15u) * va[0];
    a1 += decN((x >> 4) & 15u) * va[1];
    a0 += decN((x >> 8) & 15u) * va[2];
    a1 += decN((x >> 12) & 15u) * va[3];
    a0 += decN((x >> 16) & 15u) * vb[0];
    a1 += decN((x >> 20) & 15u) * vb[1];
    a0 += decN((x >> 24) & 15u) * vb[2];
    a1 += decN(x >> 28) * vb[3];
}
// loss: SA += Ks v, SB += nib*Ks*v
__device__ inline void dec8_loss(unsigned int x, fx4 va, fx4 vb, float& sa, float& sb) {
    #pragma unroll
    for (int k = 0; k < 8; ++k) {
        unsigned int nib = (x >> (4 * k)) & 15u;
        float g = decN(nib);
        float v = (k < 4) ? va[k] : vb[k - 4];
        float gv = g * v;
        sa += gv;
        sb += (float)nib * gv;
    }
}
// pack 8 code bytes (each 0..15) from two dwords into one dword of 8 nibs
__device__ inline unsigned int pack8(unsigned int lo, unsigned int hi) {
    unsigned int a = lo & 0x0F0F0F0Fu;
    a = (a | (a >> 4)) & 0x00FF00FFu;
    a = (a | (a >> 8)) & 0x0000FFFFu;
    unsigned int b = hi & 0x0F0F0F0Fu;
    b = (b | (b >> 4)) & 0x00FF00FFu;
    b = (b | (b >> 8)) & 0x0000FFFFu;
    return a | (b << 16);
}

// ---------------- prep: convert + row norms ----------------
__global__ __launch_bounds__(256) void prep_k(const float* __restrict__ XP,
                                              const float* __restrict__ XQ,
                                              unsigned short* __restrict__ XPb,
                                              unsigned short* __restrict__ XQb,
                                              float* __restrict__ pn,
                                              float* __restrict__ qn) {
    int task = blockIdx.x * 4 + (threadIdx.x >> 6);
    int lane = threadIdx.x & 63;
    const float* src; unsigned short* dst; float* nrm; int row;
    if (task < NN) { src = XP; dst = XPb; nrm = pn; row = task; }
    else           { src = XQ; dst = XQb; nrm = qn; row = task - NN; }
    float xv = src[row * DD + lane];
    dst[row * DD + lane] = f2bf(xv);
    float s = xv * xv;
    #pragma unroll
    for (int o = 32; o; o >>= 1) s += __shfl_xor(s, o);
    if (lane == 0) nrm[row] = s;
}

// ---------------- LDS-staged GEMM tile ----------------
__device__ inline void gemm_tile_lds(const unsigned short* __restrict__ XPb,
                                     const unsigned short* __restrict__ XQb,
                                     unsigned short* tA, unsigned short* tB,
                                     int Rblk, int Cblk, int tid,
                                     int wr, int wc, int lane, fx4 acc[4][4]) {
    const uint4* gA = (const uint4*)(XPb + (size_t)Rblk * DD);
    const uint4* gB = (const uint4*)(XQb + (size_t)Cblk * DD);
    #pragma unroll
    for (int i = 0; i < 4; ++i) {
        int c = i * 256 + tid;               // chunk 0..1023 (16B each)
        int row = c >> 3, cc = c & 7;
        int dst = row * 64 + ((cc ^ (row & 7)) << 3);
        uint4 va = gA[c];
        uint4 vb = gB[c];
        *(uint4*)(tA + dst) = va;
        *(uint4*)(tB + dst) = vb;
    }
    __syncthreads();

    int r  = lane & 15;
    int hi = lane >> 4;
    #pragma unroll
    for (int kk = 0; kk < DD; kk += 32) {
        int cbase = (kk >> 3) + hi;          // original 16B-chunk index
        short8 a[4], b[4];
        #pragma unroll
        for (int m = 0; m < 4; m++) {
            int row = wr * 64 + m * 16 + r;
            a[m] = *(const short8*)(tA + row * 64 + ((cbase ^ (row & 7)) << 3));
        }
        #pragma unroll
        for (int n = 0; n < 4; n++) {
            int row = wc * 64 + n * 16 + r;
            b[n] = *(const short8*)(tB + row * 64 + ((cbase ^ (row & 7)) << 3));
        }
        #pragma unroll
        for (int m = 0; m < 4; m++)
            #pragma unroll
            for (int n = 0; n < 4; n++)
                acc[m][n] = __builtin_amdgcn_mfma_f32_16x16x32_bf16(a[m], b[n], acc[m][n], 0, 0, 0);
    }
}

// ---------------- pass 1: per-block max -> bm[]; per-(cchunk,row) min -> rminpart ----------------
__global__ __launch_bounds__(256) void gemm_max_k(const unsigned short* __restrict__ XPb,
                                                  const unsigned short* __restrict__ XQb,
                                                  const float* __restrict__ pn,
                                                  const float* __restrict__ qn,
                                                  float* __restrict__ bm,
                                                  float* __restrict__ rminpart) {
    __shared__ unsigned short tA[128 * 64];
    __shared__ unsigned short tB[128 * 64];
    int w = threadIdx.x >> 6, wr = w >> 1, wc = w & 1;
    int lane = threadIdx.x & 63;
    int R0 = blockIdx.y * 128 + wr * 64;
    int C0 = blockIdx.x * 128 + wc * 64;
    fx4 acc[4][4] = {};
    gemm_tile_lds(XPb, XQb, tA, tB, blockIdx.y * 128, blockIdx.x * 128,
                  threadIdx.x, wr, wc, lane, acc);

    float pl = pn[R0 + lane], ql = qn[C0 + lane];
    float pr[16], qc[4];
    #pragma unroll
    for (int m = 0; m < 4; m++)
        #pragma unroll
        for (int j = 0; j < 4; j++)
            pr[m * 4 + j] = __shfl(pl, m * 16 + ((lane >> 4) << 2) + j);
    #pragma unroll
    for (int n = 0; n < 4; n++) qc[n] = __shfl(ql, n * 16 + (lane & 15));

    float mx = 0.0f;
    float mn[16];
    #pragma unroll
    for (int m = 0; m < 4; m++) {
        #pragma unroll
        for (int j = 0; j < 4; j++) {
            float lmn = 1e30f;
            #pragma unroll
            for (int n = 0; n < 4; n++) {
                float c = fmaxf(pr[m * 4 + j] + qc[n] - 2.0f * acc[m][n][j], 0.0f);
                mx = fmaxf(mx, c);
                lmn = fminf(lmn, c);
            }
            mn[m * 4 + j] = lmn;
        }
    }
    #pragma unroll
    for (int o = 1; o < 16; o <<= 1) {
        #pragma unroll
        for (int e = 0; e < 16; e++) mn[e] = fminf(mn[e], __shfl_xor(mn[e], o));
    }
    if ((lane & 15) == 0) {
        int hi = lane >> 4;
        int cchunk = blockIdx.x * 2 + wc;
        #pragma unroll
        for (int m = 0; m < 4; m++)
            #pragma unroll
            for (int j = 0; j < 4; j++)
                rminpart[(size_t)cchunk * NN + blockIdx.y * 128 + wr * 64 + m * 16 + hi * 4 + j]
                    = mn[m * 4 + j];
    }

    #pragma unroll
    for (int o = 32; o; o >>= 1) mx = fmaxf(mx, __shfl_xor(mx, o));
    __shared__ float wmax[4];
    if (lane == 0) wmax[w] = mx;
    __syncthreads();
    if (threadIdx.x == 0)
        bm[blockIdx.y * 64 + blockIdx.x] = fmaxf(fmaxf(wmax[0], wmax[1]), fmaxf(wmax[2], wmax[3]));
}

// ---------------- reduce bm[4096] -> regbuf {reg, inv_reg} ----------------
__global__ __launch_bounds__(256) void max_red_k(const float* __restrict__ bm,
                                                 float* __restrict__ regbuf) {
    int t = threadIdx.x;
    float mx = 0.0f;
    #pragma unroll
    for (int i = 0; i < 16; ++i) mx = fmaxf(mx, bm[i * 256 + t]);
    #pragma unroll
    for (int o = 32; o; o >>= 1) mx = fmaxf(mx, __shfl_xor(mx, o));
    __shared__ float wmax[4];
    if ((t & 63) == 0) wmax[t >> 6] = mx;
    __syncthreads();
    if (t == 0) {
        float m = fmaxf(fmaxf(wmax[0], wmax[1]), fmaxf(wmax[2], wmax[3]));
        float reg = EPSV * m;
        regbuf[0] = reg;
        regbuf[1] = 1.0f / reg;
    }
}

// ---------------- per-row min + u'0 = exp(-mn/reg)/N ----------------
__global__ __launch_bounds__(256) void scale2_k(const float* __restrict__ rminpart,
                                                const float* __restrict__ regbuf,
                                                float* __restrict__ mnrow,
                                                float* __restrict__ uu0) {
    int row = blockIdx.x * 256 + threadIdx.x;
    float mn = 1e30f;
    #pragma unroll 8
    for (int c = 0; c < 128; ++c) mn = fminf(mn, rminpart[(size_t)c * NN + row]);
    mnrow[row] = mn;
    uu0[row] = __expf(-mn * regbuf[1]) / (float)NN;
}

// ---------------- pass 2: 4-bit codes; ONE pass stores BOTH Ks and KsT ----------------
__global__ __launch_bounds__(256) void gemm_K_k(const unsigned short* __restrict__ XPb,
                                                const unsigned short* __restrict__ XQb,
                                                const float* __restrict__ pn,
                                                const float* __restrict__ qn,
                                                const float* __restrict__ regbuf,
                                                const float* __restrict__ mnrow,
                                                unsigned char* __restrict__ Kb4,
                                                unsigned char* __restrict__ KTb4) {
    __shared__ unsigned short tA[128 * 64];
    __shared__ unsigned short tB[128 * 64];
    __shared__ unsigned char tile[128][136];
    __shared__ unsigned char tileT[128][136];
    int w = threadIdx.x >> 6, wr = w >> 1, wc = w & 1;
    int lane = threadIdx.x & 63;
    int R0 = blockIdx.y * 128 + wr * 64;
    int C0 = blockIdx.x * 128 + wc * 64;
    fx4 acc[4][4] = {};
    gemm_tile_lds(XPb, XQb, tA, tB, blockIdx.y * 128, blockIdx.x * 128,
                  threadIdx.x, wr, wc, lane, acc);

    float k1 = regbuf[1] * INVLN2F;            // codes per C-unit = 1/(reg*ln2)
    float pl = pn[R0 + lane], ql = qn[C0 + lane];
    float mnl = mnrow[R0 + lane];
    float pr[16], qc[4], mnr[16];
    #pragma unroll
    for (int m = 0; m < 4; m++)
        #pragma unroll
        for (int j = 0; j < 4; j++) {
            int src = m * 16 + ((lane >> 4) << 2) + j;
            pr[m * 4 + j]  = __shfl(pl, src);
            mnr[m * 4 + j] = __shfl(mnl, src);
        }
    #pragma unroll
    for (int n = 0; n < 4; n++) qc[n] = __shfl(ql, n * 16 + (lane & 15));

    #pragma unroll
    for (int m = 0; m < 4; m++) {
        #pragma unroll
        for (int n = 0; n < 4; n++) {
            #pragma unroll
            for (int j = 0; j < 4; j++) {
                float c = fmaxf(pr[m * 4 + j] + qc[n] - 2.0f * acc[m][n][j], 0.0f);
                int L = (int)(fmaf(c - mnr[m * 4 + j], k1, 0.5f));
                L = L < 0 ? 0 : (L > 15 ? 15 : L);
                int lr = wr * 64 + m * 16 + ((lane >> 4) << 2) + j;
                int lc = wc * 64 + n * 16 + (lane & 15);
                tile[lr][lc]  = (unsigned char)L;
                tileT[lc][lr] = (unsigned char)L;
            }
        }
    }
    __syncthreads();

    int lane16 = threadIdx.x & 15;
    int rowgrp = threadIdx.x >> 4;
    size_t Rg = (size_t)blockIdx.y * 128;
    size_t Cg = (size_t)blockIdx.x * 128;
    #pragma unroll
    for (int s = 0; s < 8; ++s) {
        int row = s * 16 + rowgrp;
        uint2 pk = *(const uint2*)&tile[row][lane16 * 8];
        *(unsigned int*)(Kb4 + (Rg + row) * (NN / 2) + (Cg >> 1) + lane16 * 4) = pack8(pk.x, pk.y);
        uint2 pt = *(const uint2*)&tileT[row][lane16 * 8];
        *(unsigned int*)(KTb4 + (Cg + row) * (NN / 2) + (Rg >> 1) + lane16 * 4) = pack8(pt.x, pt.y);
    }
}

// ---------------- row-gather matvec v3, 4-bit: wout = (1/N)/(M win) ----------------
// block = 16 rows x 512 thr (8 waves), grid 512 -> per-pass v-broadcast
// traffic halved to 16 MB. Lane owns 16 contiguous cols (8B codes/row).
// Codes in 2 batches of 8 rows (VGPR ~60). Cross-wave partials in 32 KB LDS.
__global__ __launch_bounds__(512) void mv_k(const unsigned char* __restrict__ M4,
                                            const float* __restrict__ win,
                                            float* __restrict__ wout) {
    __shared__ float xp[8][16][64];   // [wave][row][lane] = 32 KiB
    int t = threadIdx.x;
    int w = t >> 6, l = t & 63;
    int row0 = blockIdx.x << 4;
    int cb = (w << 10) + (l << 4);                    // 16 cols per lane
    const unsigned char* Mp = M4 + (size_t)row0 * (NN / 2) + (cb >> 1);

    fx4 v0 = *(const fx4*)(win + cb);
    fx4 v1 = *(const fx4*)(win + cb + 4);
    fx4 v2 = *(const fx4*)(win + cb + 8);
    fx4 v3 = *(const fx4*)(win + cb + 12);

    #pragma unroll
    for (int b = 0; b < 2; ++b) {
        uint2 cw[8];
        #pragma unroll
        for (int r = 0; r < 8; ++r)
            cw[r] = *(const uint2*)(Mp + (size_t)(b * 8 + r) * (NN / 2));
        #pragma unroll
        for (int r = 0; r < 8; ++r) {
            float a0 = 0.0f, a1 = 0.0f;
            dec8_dot(cw[r].x, v0, v1, a0, a1);
            dec8_dot(cw[r].y, v2, v3, a0, a1);
            xp[w][b * 8 + r][l] = a0 + a1;
        }
    }
    __syncthreads();

    // wave w reduces rows 2w, 2w+1: 8 wave-chunks x 64 lanes each
    #pragma unroll
    for (int k = 0; k < 2; ++k) {
        int rr = (w << 1) + k;
        float s = 0.0f;
        #pragma unroll
        for (int q = 0; q < 8; ++q)
            s += xp[q][rr][l];
        #pragma unroll
        for (int o = 32; o; o >>= 1) s += __shfl_xor(s, o);
        if (l == 0) wout[row0 + rr] = (1.0f / (float)NN) / s;
    }
}

// ---------------- loss pass: SA = sum Ks v, SB = sum nib*Ks*v -> tt = SB/SA ----------------
__global__ __launch_bounds__(256) void loss_k(const unsigned char* __restrict__ Kb4,
                                              const float* __restrict__ vv,
                                              float* __restrict__ tt) {
    __shared__ float xrA[4][16];
    __shared__ float xrB[4][16];
    int t = threadIdx.x;
    int w = t >> 6, l = t & 63;
    size_t r0 = (size_t)blockIdx.x * 16;
    int cb = (w << 11) + (l << 5);
    fx4 vr[8];
    #pragma unroll
    for (int q = 0; q < 8; ++q)
        vr[q] = *(const fx4*)(vv + cb + q * 4);

    #pragma unroll
    for (int i = 0; i < 16; ++i) {
        float sa = 0.0f, sb = 0.0f;
        uint4 q = *(const uint4*)(Kb4 + (r0 + i) * (NN / 2) + (cb >> 1));
        dec8_loss(q.x, vr[0], vr[1], sa, sb);
        dec8_loss(q.y, vr[2], vr[3], sa, sb);
        dec8_loss(q.z, vr[4], vr[5], sa, sb);
        dec8_loss(q.w, vr[6], vr[7], sa, sb);
        #pragma unroll
        for (int o = 32; o; o >>= 1) {
            sa += __shfl_xor(sa, o);
            sb += __shfl_xor(sb, o);
        }
        if (l == 0) { xrA[w][i] = sa; xrB[w][i] = sb; }
    }
    __syncthreads();
    if (t < 16) {
        float A = xrA[0][t] + xrA[1][t] + xrA[2][t] + xrA[3][t];
        float B = xrB[0][t] + xrB[1][t] + xrB[2][t] + xrB[3][t];
        tt[r0 + t] = B / A;
    }
}

// ---------------- out = (1/N) * sum_i (mn_i + reg*ln2*tt_i) ----------------
__global__ __launch_bounds__(256) void final_loss_k(const float* __restrict__ mnrow,
                                                    const float* __restrict__ tt,
                                                    const float* __restrict__ regbuf,
                                                    float* __restrict__ out) {
    int t = threadIdx.x;
    float c1 = regbuf[0] * LN2F;
    float s = 0.0f;
    for (int i = t; i < NN; i += 256)
        s += mnrow[i] + c1 * tt[i];
    #pragma unroll
    for (int o = 32; o; o >>= 1) s += __shfl_xor(s, o);
    __shared__ float wsum[4];
    if ((t & 63) == 0) wsum[t >> 6] = s;
    __syncthreads();
    if (t == 0)
        out[0] = (wsum[0] + wsum[1] + wsum[2] + wsum[3]) / (float)NN;
}

extern "C" void kernel_launch(void* const* d_in, const int* in_sizes, int n_in,
                              void* d_out, int out_size, void* d_ws, size_t ws_size,
                              hipStream_t stream) {
    const float* XP = (const float*)d_in[0];
    const float* XQ = (const float*)d_in[1];
    float* out = (float*)d_out;

    // workspace layout (~72.5 MiB)
    char* p = (char*)d_ws;
    unsigned char* Kb4  = (unsigned char*)p;   p += (size_t)NN * NN / 2;      // 32 MiB
    unsigned char* KTb4 = (unsigned char*)p;   p += (size_t)NN * NN / 2;      // 32 MiB
    unsigned short* XPb = (unsigned short*)p;  p += (size_t)NN * DD * 2;      // 1 MiB
    unsigned short* XQb = (unsigned short*)p;  p += (size_t)NN * DD * 2;      // 1 MiB
    float* rminpart = (float*)p;               p += (size_t)128 * NN * 4;     // 4 MiB
    float* pn = (float*)p;                     p += NN * 4;
    float* qn = (float*)p;                     p += NN * 4;
    float* vv = (float*)p;                     p += NN * 4;
    float* uu = (float*)p;                     p += NN * 4;
    float* tt = (float*)p;                     p += NN * 4;
    float* mnrow = (float*)p;                  p += NN * 4;
    float* bm = (float*)p;                     p += 4096 * 4;
    float* regbuf = (float*)p;

    prep_k<<<4096, 256, 0, stream>>>(XP, XQ, XPb, XQb, pn, qn);
    gemm_max_k<<<dim3(64, 64), 256, 0, stream>>>(XPb, XQb, pn, qn, bm, rminpart);
    max_red_k<<<1, 256, 0, stream>>>(bm, regbuf);
    scale2_k<<<32, 256, 0, stream>>>(rminpart, regbuf, mnrow, uu);   // mnrow + u'0 in uu
    gemm_K_k<<<dim3(64, 64), 256, 0, stream>>>(XPb, XQb, pn, qn, regbuf, mnrow, Kb4, KTb4);

    // v1 = (1/N)/(KsT u'0)
    mv_k<<<512, 512, 0, stream>>>(KTb4, uu, vv);
    for (int it = 1; it < NITER; ++it) {
        mv_k<<<512, 512, 0, stream>>>(Kb4, vv, uu);    // u' = (1/N)/(Ks v)
        mv_k<<<512, 512, 0, stream>>>(KTb4, uu, vv);   // v  = (1/N)/(KsT u')
    }
    loss_k<<<512, 256, 0, stream>>>(Kb4, vv, tt);
    final_loss_k<<<1, 256, 0, stream>>>(mnrow, tt, regbuf, out);
}